// Round 5
// baseline (792.276 us; speedup 1.0000x reference)
//
#include <hip/hip_runtime.h>
#include <hip/hip_bf16.h>
#include <math.h>

// N=10000, E=160000, C=16, C0=32, L=2, M=5, H=8, R_IN=32, R_HID=128, REQ=384

typedef short bf16x8 __attribute__((ext_vector_type(8)));
typedef float f32x4 __attribute__((ext_vector_type(4)));

__device__ __forceinline__ float waveSum(float v) {
#pragma unroll
  for (int m = 1; m < 64; m <<= 1) v += __shfl_xor(v, m, 64);
  return v;
}
__device__ __forceinline__ unsigned encf(float f) {
  unsigned u = __float_as_uint(f);
  return (u & 0x80000000u) ? ~u : (u | 0x80000000u);
}
__device__ __forceinline__ float decf(unsigned u) {
  return (u & 0x80000000u) ? __uint_as_float(u & 0x7FFFFFFFu) : __uint_as_float(~u);
}
__device__ __forceinline__ unsigned short f2bu(float f) {
  __hip_bfloat16 h = __float2bfloat16(f);
  unsigned short u;
  __builtin_memcpy(&u, &h, 2);
  return u;
}

// ---------------------------------------------------------------------------
// Prep: transpose radial weights to bf16 [n][k] layout
// ---------------------------------------------------------------------------
__global__ __launch_bounds__(256) void prep_kernel(
    const float* __restrict__ W1, const float* __restrict__ W2,
    const float* __restrict__ W3,
    unsigned short* __restrict__ W1T, unsigned short* __restrict__ W2T,
    unsigned short* __restrict__ W3T) {
  int idx = blockIdx.x * 256 + threadIdx.x;
  if (idx < 128 * 32) {
    int n = idx >> 5, k = idx & 31;
    W1T[idx] = f2bu(W1[k * 128 + n]);
  }
  int i2 = idx - 128 * 32;
  if (i2 >= 0 && i2 < 128 * 128) {
    int n = i2 >> 7, k = i2 & 127;
    W2T[i2] = f2bu(W2[k * 128 + n]);
  }
  int i3 = idx - 128 * 32 - 128 * 128;
  if (i3 >= 0 && i3 < 384 * 128) {
    int n = i3 >> 7, k = i3 & 127;
    W3T[i3] = f2bu(W3[k * 384 + n]);
  }
}

// ---------------------------------------------------------------------------
// Node prep: hoist channel-mix GEMMs from edges to nodes.
// ---------------------------------------------------------------------------
__global__ __launch_bounds__(256) void nodeprep_kernel(
    const float* __restrict__ xt, const float* __restrict__ xt0,
    const float* __restrict__ xs, const float* __restrict__ xs0,
    const float* __restrict__ qW, const float* __restrict__ qW0,
    const float* __restrict__ qb0, const float* __restrict__ qng0,
    const float* __restrict__ kvW, const float* __restrict__ kvW0,
    const float* __restrict__ kvb0,
    float* __restrict__ qmixN, float* __restrict__ q0N,
    float* __restrict__ kvmixN, float* __restrict__ kv0N, int N) {
  __shared__ float sXT[4][160];
  __shared__ float sXS[4][160];
  __shared__ float sX0T[4][32];
  __shared__ float sX0S[4][32];
  const int tid = threadIdx.x, wv = tid >> 6, w = tid & 63;
  const int n = blockIdx.x * 4 + wv;
  if (n < N) {
    for (int i = w; i < 160; i += 64) {
      sXT[wv][i] = xt[(size_t)n * 160 + i];
      sXS[wv][i] = xs[(size_t)n * 160 + i];
    }
    if (w < 32) { sX0T[wv][w] = xt0[n * 32 + w]; sX0S[wv][w] = xs0[n * 32 + w]; }
  }
  __syncthreads();
  if (n >= N) return;
  for (int i = w; i < 160; i += 64) {
    int o = i / 10, lm = i % 10, l = lm / 5;
    const float4* wr = (const float4*)(qW + l * 256 + o * 16);
    float a = 0.f;
#pragma unroll
    for (int c4 = 0; c4 < 4; c4++) {
      float4 ww = wr[c4];
      a += ww.x * sXT[wv][(c4 * 4 + 0) * 10 + lm] + ww.y * sXT[wv][(c4 * 4 + 1) * 10 + lm]
         + ww.z * sXT[wv][(c4 * 4 + 2) * 10 + lm] + ww.w * sXT[wv][(c4 * 4 + 3) * 10 + lm];
    }
    qmixN[(size_t)n * 160 + i] = a;
  }
  for (int i = w; i < 320; i += 64) {
    int o = i / 10, lm = i % 10, l = lm / 5;
    const float4* wr = (const float4*)(kvW + l * 512 + o * 16);
    float a = 0.f;
#pragma unroll
    for (int c4 = 0; c4 < 4; c4++) {
      float4 ww = wr[c4];
      a += ww.x * sXS[wv][(c4 * 4 + 0) * 10 + lm] + ww.y * sXS[wv][(c4 * 4 + 1) * 10 + lm]
         + ww.z * sXS[wv][(c4 * 4 + 2) * 10 + lm] + ww.w * sXS[wv][(c4 * 4 + 3) * 10 + lm];
    }
    kvmixN[(size_t)n * 320 + i] = a;
  }
  {
    float a = 0.f;
    if (w < 32) {
      a = qb0[w];
      const float4* wr = (const float4*)(qW0 + w * 32);
#pragma unroll
      for (int c4 = 0; c4 < 8; c4++) {
        float4 ww = wr[c4];
        a += ww.x * sX0T[wv][c4 * 4] + ww.y * sX0T[wv][c4 * 4 + 1]
           + ww.z * sX0T[wv][c4 * 4 + 2] + ww.w * sX0T[wv][c4 * 4 + 3];
      }
    }
    float vv = (w < 32) ? a : 0.f;
    float s1 = waveSum(vv), s2 = waveSum(vv * vv);
    float mu = s1 / 32.f, var = s2 / 32.f - mu * mu;
    if (w < 32) q0N[(size_t)n * 32 + w] = (a - mu) * rsqrtf(var + 1e-5f) * qng0[w];
  }
  {
    float a = kvb0[w];
    const float4* wr = (const float4*)(kvW0 + w * 32);
#pragma unroll
    for (int c4 = 0; c4 < 8; c4++) {
      float4 ww = wr[c4];
      a += ww.x * sX0S[wv][c4 * 4] + ww.y * sX0S[wv][c4 * 4 + 1]
         + ww.z * sX0S[wv][c4 * 4 + 2] + ww.w * sX0S[wv][c4 * 4 + 3];
    }
    kv0N[(size_t)n * 64 + w] = a;
  }
}

// ---------------------------------------------------------------------------
// Kernel 1: MFMA radial MLP (unchanged)
// ---------------------------------------------------------------------------
__global__ __launch_bounds__(256) void radial_mfma(
    const float* __restrict__ ef,
    const unsigned short* __restrict__ W1T, const unsigned short* __restrict__ W2T,
    const unsigned short* __restrict__ W3T,
    const float* __restrict__ b1, const float* __restrict__ g1, const float* __restrict__ be1,
    const float* __restrict__ b2, const float* __restrict__ g2, const float* __restrict__ be2,
    const float* __restrict__ b3,
    float* __restrict__ w_chunk, int e0, int E) {
  __shared__ unsigned short sA[128 * 128];
  __shared__ unsigned short sW[128 * 128];
  const int tid = threadIdx.x;
  const int lane = tid & 63, wid = tid >> 6;
  const int eb = blockIdx.x * 128;
  const int colq = lane & 15, rowq = lane >> 4;

  float b1v[8], g1v[8], be1v[8], b2v[8], g2v[8], be2v[8];
#pragma unroll
  for (int nt = 0; nt < 8; nt++) {
    int c = nt * 16 + colq;
    b1v[nt] = b1[c]; g1v[nt] = g1[c]; be1v[nt] = be1[c];
    b2v[nt] = b2[c]; g2v[nt] = g2[c]; be2v[nt] = be2[c];
  }

  for (int idx = tid; idx < 1024; idx += 256) {
    int e = idx >> 3, k4 = idx & 7;
    int ee = e0 + eb + e; if (ee >= E) ee = E - 1;
    float4 v = *(const float4*)&ef[(size_t)ee * 32 + k4 * 4];
    ushort4 uu = make_ushort4(f2bu(v.x), f2bu(v.y), f2bu(v.z), f2bu(v.w));
    unsigned bo = (unsigned)e * 256 + (((unsigned)k4 * 8) ^ ((e & 7) << 4));
    *(ushort4*)((char*)sA + bo) = uu;
  }
  for (int idx = tid; idx < 512; idx += 256) {
    int n = idx >> 2, j = idx & 3;
    uint4 v = *(const uint4*)&W1T[n * 32 + j * 8];
    unsigned bo = (unsigned)n * 256 + (((unsigned)j * 16) ^ ((n & 7) << 4));
    *(uint4*)((char*)sW + bo) = v;
  }
  __syncthreads();

  f32x4 zz = {0.f, 0.f, 0.f, 0.f};
  f32x4 acc[2][8];
#pragma unroll
  for (int mt = 0; mt < 2; mt++)
#pragma unroll
    for (int nt = 0; nt < 8; nt++) acc[mt][nt] = zz;

  {
    bf16x8 af[2];
#pragma unroll
    for (int mt = 0; mt < 2; mt++) {
      int row = wid * 32 + mt * 16 + colq;
      unsigned bo = (unsigned)row * 256 + (((unsigned)rowq * 16) ^ ((row & 7) << 4));
      af[mt] = *(const bf16x8*)((const char*)sA + bo);
    }
#pragma unroll
    for (int nt = 0; nt < 8; nt++) {
      int n = nt * 16 + colq;
      unsigned bo = (unsigned)n * 256 + (((unsigned)rowq * 16) ^ ((n & 7) << 4));
      bf16x8 bfv = *(const bf16x8*)((const char*)sW + bo);
#pragma unroll
      for (int mt = 0; mt < 2; mt++)
        acc[mt][nt] = __builtin_amdgcn_mfma_f32_16x16x32_bf16(af[mt], bfv, acc[mt][nt], 0, 0, 0);
    }
  }
  __syncthreads();

#pragma unroll
  for (int mt = 0; mt < 2; mt++) {
#pragma unroll
    for (int r = 0; r < 4; r++) {
      float s1 = 0.f, s2 = 0.f;
#pragma unroll
      for (int nt = 0; nt < 8; nt++) {
        float v = acc[mt][nt][r] + b1v[nt];
        s1 += v; s2 += v * v;
      }
#pragma unroll
      for (int off = 1; off < 16; off <<= 1) { s1 += __shfl_xor(s1, off, 64); s2 += __shfl_xor(s2, off, 64); }
      float mu = s1 * (1.f / 128.f);
      float rs = rsqrtf(s2 * (1.f / 128.f) - mu * mu + 1e-5f);
      int row = wid * 32 + mt * 16 + rowq * 4 + r;
      unsigned rbase = (unsigned)row * 256;
      unsigned swz = (row & 7) << 4;
#pragma unroll
      for (int nt = 0; nt < 8; nt++) {
        float v = (acc[mt][nt][r] + b1v[nt] - mu) * rs * g1v[nt] + be1v[nt];
        v = v / (1.f + __expf(-v));
        *(unsigned short*)((char*)sA + rbase + ((((unsigned)(nt * 16 + colq)) * 2) ^ swz)) = f2bu(v);
      }
    }
  }
  for (int idx = tid; idx < 2048; idx += 256) {
    int n = idx >> 4, j = idx & 15;
    uint4 v = *(const uint4*)&W2T[n * 128 + j * 8];
    unsigned bo = (unsigned)n * 256 + (((unsigned)j * 16) ^ ((n & 7) << 4));
    *(uint4*)((char*)sW + bo) = v;
  }
  __syncthreads();

#pragma unroll
  for (int mt = 0; mt < 2; mt++)
#pragma unroll
    for (int nt = 0; nt < 8; nt++) acc[mt][nt] = zz;
#pragma unroll
  for (int ks = 0; ks < 4; ks++) {
    bf16x8 af[2];
#pragma unroll
    for (int mt = 0; mt < 2; mt++) {
      int row = wid * 32 + mt * 16 + colq;
      unsigned bo = (unsigned)row * 256 + (((unsigned)(ks * 64 + rowq * 16)) ^ ((row & 7) << 4));
      af[mt] = *(const bf16x8*)((const char*)sA + bo);
    }
#pragma unroll
    for (int nt = 0; nt < 8; nt++) {
      int n = nt * 16 + colq;
      unsigned bo = (unsigned)n * 256 + (((unsigned)(ks * 64 + rowq * 16)) ^ ((n & 7) << 4));
      bf16x8 bfv = *(const bf16x8*)((const char*)sW + bo);
#pragma unroll
      for (int mt = 0; mt < 2; mt++)
        acc[mt][nt] = __builtin_amdgcn_mfma_f32_16x16x32_bf16(af[mt], bfv, acc[mt][nt], 0, 0, 0);
    }
  }
  __syncthreads();

#pragma unroll
  for (int mt = 0; mt < 2; mt++) {
#pragma unroll
    for (int r = 0; r < 4; r++) {
      float s1 = 0.f, s2 = 0.f;
#pragma unroll
      for (int nt = 0; nt < 8; nt++) {
        float v = acc[mt][nt][r] + b2v[nt];
        s1 += v; s2 += v * v;
      }
#pragma unroll
      for (int off = 1; off < 16; off <<= 1) { s1 += __shfl_xor(s1, off, 64); s2 += __shfl_xor(s2, off, 64); }
      float mu = s1 * (1.f / 128.f);
      float rs = rsqrtf(s2 * (1.f / 128.f) - mu * mu + 1e-5f);
      int row = wid * 32 + mt * 16 + rowq * 4 + r;
      unsigned rbase = (unsigned)row * 256;
      unsigned swz = (row & 7) << 4;
#pragma unroll
      for (int nt = 0; nt < 8; nt++) {
        float v = (acc[mt][nt][r] + b2v[nt] - mu) * rs * g2v[nt] + be2v[nt];
        v = v / (1.f + __expf(-v));
        *(unsigned short*)((char*)sA + rbase + ((((unsigned)(nt * 16 + colq)) * 2) ^ swz)) = f2bu(v);
      }
    }
  }

  for (int cc = 0; cc < 3; cc++) {
    if (cc > 0) __syncthreads();
    for (int idx = tid; idx < 2048; idx += 256) {
      int n = idx >> 4, j = idx & 15;
      uint4 v = *(const uint4*)&W3T[(size_t)(cc * 128 + n) * 128 + j * 8];
      unsigned bo = (unsigned)n * 256 + (((unsigned)j * 16) ^ ((n & 7) << 4));
      *(uint4*)((char*)sW + bo) = v;
    }
    __syncthreads();
    f32x4 a3[2][8];
#pragma unroll
    for (int mt = 0; mt < 2; mt++)
#pragma unroll
      for (int nt = 0; nt < 8; nt++) a3[mt][nt] = zz;
#pragma unroll
    for (int ks = 0; ks < 4; ks++) {
      bf16x8 af[2];
#pragma unroll
      for (int mt = 0; mt < 2; mt++) {
        int row = wid * 32 + mt * 16 + colq;
        unsigned bo = (unsigned)row * 256 + (((unsigned)(ks * 64 + rowq * 16)) ^ ((row & 7) << 4));
        af[mt] = *(const bf16x8*)((const char*)sA + bo);
      }
#pragma unroll
      for (int nt = 0; nt < 8; nt++) {
        int n = nt * 16 + colq;
        unsigned bo = (unsigned)n * 256 + (((unsigned)(ks * 64 + rowq * 16)) ^ ((n & 7) << 4));
        bf16x8 bfv = *(const bf16x8*)((const char*)sW + bo);
#pragma unroll
        for (int mt = 0; mt < 2; mt++)
          a3[mt][nt] = __builtin_amdgcn_mfma_f32_16x16x32_bf16(af[mt], bfv, a3[mt][nt], 0, 0, 0);
      }
    }
#pragma unroll
    for (int nt = 0; nt < 8; nt++) {
      int col = cc * 128 + nt * 16 + colq;
      float b3v = b3[col];
#pragma unroll
      for (int mt = 0; mt < 2; mt++) {
#pragma unroll
        for (int r = 0; r < 4; r++) {
          int row_e = eb + wid * 32 + mt * 16 + rowq * 4 + r;
          w_chunk[(size_t)row_e * 384 + col] = a3[mt][nt][r] + b3v;
        }
      }
    }
  }
}

// ---------------------------------------------------------------------------
// Kernel 2: per-edge rotate+conv+norm+logits, REGISTER-ONLY (no LDS/barriers).
// Lane g = o*2+l owns the 5 m-values of kv group (o,l); q on lanes g<32.
// ---------------------------------------------------------------------------
template <int STOREV>
__global__ __launch_bounds__(256) void edgeA_kernel(
    const float* __restrict__ qmixN, const float* __restrict__ q0N,
    const float* __restrict__ kvmixN, const float* __restrict__ kv0N,
    const float* __restrict__ Rw, const int* __restrict__ edge,
    const float* __restrict__ w_chunk, int e0,
    const float* __restrict__ qng, const float* __restrict__ kng,
    const float* __restrict__ kng0,
    __hip_bfloat16* __restrict__ v_buf, __hip_bfloat16* __restrict__ v0_buf,
    float* __restrict__ logits, unsigned* __restrict__ mx, int E) {
  const int g = threadIdx.x & 63;
  const int e = e0 + blockIdx.x * 4 + (threadIdx.x >> 6);
  const int src = edge[e], dst = edge[E + e];
  const int l = g & 1, cg = g >> 1;

  // R rows for this lane's l: R[m][n] = Rw[e*50 + l*25 + m*5 + n]
  float R[5][5];
  {
    const float* rb = Rw + (size_t)e * 50 + l * 25;
#pragma unroll
    for (int m = 0; m < 5; m++)
#pragma unroll
      for (int n = 0; n < 5; n++) R[m][n] = rb[m * 5 + n];
  }
  // kv: gather + rotate (in-lane)
  float xr[5];
  {
    const float* xb = kvmixN + (size_t)src * 320 + g * 5;
    float x0 = xb[0], x1 = xb[1], x2 = xb[2], x3 = xb[3], x4 = xb[4];
#pragma unroll
    for (int m = 0; m < 5; m++)
      xr[m] = R[m][0] * x0 + R[m][1] * x1 + R[m][2] * x2 + R[m][3] * x3 + R[m][4] * x4;
  }
  // SO(2) conv (in-lane; weights lane-contiguous)
  const float* wa = w_chunk + (size_t)(e - e0) * 384;
  float w0_ = wa[4 * g], w1_ = wa[4 * g + 1], w2_ = wa[4 * g + 2], w3_ = wa[4 * g + 3];
  float wm = wa[320 + g];
  float y[5];
  y[0] = w3_ * xr[4] + w1_ * xr[0];
  y[1] = w2_ * xr[3] + w0_ * xr[1];
  y[2] = wm * xr[2];
  y[3] = w0_ * xr[3] - w2_ * xr[1];
  y[4] = w1_ * xr[4] - w3_ * xr[0];
  float y0 = wa[256 + g] * kv0N[(size_t)src * 64 + g];

  // k eq_norm (lanes g<32 are k)
  float p = 0.f;
  if (g < 32) p = y[0] * y[0] + y[1] * y[1] + y[2] * y[2] + y[3] * y[3] + y[4] * y[4];
  float rmsk = rsqrtf(waveSum(p) * (1.f / 160.f) + 1e-5f);
  float kngc = (g < 32) ? kng[cg] : 0.f;
  float yk[5];
#pragma unroll
  for (int m = 0; m < 5; m++) yk[m] = y[m] * rmsk * kngc;
  // k0 LN over lanes g<32
  float k0v = (g < 32) ? y0 : 0.f;
  float s1 = waveSum(k0v), s2 = waveSum(k0v * k0v);
  float mu = s1 * (1.f / 32.f), var = s2 * (1.f / 32.f) - mu * mu;
  float k0n = (k0v - mu) * rsqrtf(var + 1e-5f) * ((g < 32) ? kng0[g] : 0.f);

  // q: gather + rotate + eq_norm (lanes g<32)
  float qn[5];
  float q0 = 0.f;
  {
    float qx0 = 0.f, qx1 = 0.f, qx2 = 0.f, qx3 = 0.f, qx4 = 0.f;
    if (g < 32) {
      const float* qb = qmixN + (size_t)dst * 160 + g * 5;
      qx0 = qb[0]; qx1 = qb[1]; qx2 = qb[2]; qx3 = qb[3]; qx4 = qb[4];
      q0 = q0N[(size_t)dst * 32 + g];
    }
    float qr[5];
#pragma unroll
    for (int m = 0; m < 5; m++)
      qr[m] = R[m][0] * qx0 + R[m][1] * qx1 + R[m][2] * qx2 + R[m][3] * qx3 + R[m][4] * qx4;
    float pq = qr[0] * qr[0] + qr[1] * qr[1] + qr[2] * qr[2] + qr[3] * qr[3] + qr[4] * qr[4];
    float rmsq = rsqrtf(waveSum(pq) * (1.f / 160.f) + 1e-5f);
    float qngc = (g < 32) ? qng[cg] : 0.f;
#pragma unroll
    for (int m = 0; m < 5; m++) qn[m] = qr[m] * rmsq * qngc;
  }

  // logits: head h = g>>2 lives on lanes 4h..4h+3 (vector AND scalar parts)
  float part = qn[0] * yk[0] + qn[1] * yk[1] + qn[2] * yk[2] + qn[3] * yk[3] + qn[4] * yk[4]
             + q0 * k0n;
  part += __shfl_xor(part, 1, 64);
  part += __shfl_xor(part, 2, 64);
  if (g < 32 && (g & 3) == 0) {
    int h = g >> 2;
    float lg = part * 0.70710678118654752f;
    logits[(size_t)e * 8 + h] = lg;
    atomicMax(&mx[dst * 8 + h], encf(lg));
  }
  // v store (lanes g>=32 are v)
  if (STOREV && g >= 32) {
    int j = g - 32;
#pragma unroll
    for (int m = 0; m < 5; m++)
      v_buf[(size_t)e * 160 + j * 5 + m] = __float2bfloat16(y[m]);
    v0_buf[(size_t)e * 32 + j] = __float2bfloat16(y0);
  }
}

// ---------------------------------------------------------------------------
// Kernel 3: denominator
// ---------------------------------------------------------------------------
__global__ __launch_bounds__(256) void edge2_kernel(
    const int* __restrict__ edge, const float* __restrict__ logits,
    const unsigned* __restrict__ mx, float* __restrict__ den, int E) {
  int idx = blockIdx.x * 256 + threadIdx.x;
  if (idx >= E * 8) return;
  int e = idx >> 3, h = idx & 7;
  int dst = edge[E + e];
  float m = decf(mx[dst * 8 + h]);
  atomicAdd(&den[dst * 8 + h], __expf(logits[idx] - m));
}

// ---------------------------------------------------------------------------
// Kernel 4a (fast): alpha*v, inverse rotation, scatter — REGISTER-ONLY.
// ---------------------------------------------------------------------------
__global__ __launch_bounds__(256) void edgeB_light(
    const float* __restrict__ Rw, const int* __restrict__ edge,
    const __hip_bfloat16* __restrict__ v_buf, const __hip_bfloat16* __restrict__ v0_buf,
    const float* __restrict__ logits, const unsigned* __restrict__ mx,
    const float* __restrict__ den,
    float* __restrict__ att, float* __restrict__ att0, int E) {
  const int g = threadIdx.x & 63;
  const int e = blockIdx.x * 4 + (threadIdx.x >> 6);
  const int dst = edge[E + e];
  const int l = g & 1;
  const int h = (g < 32) ? (g >> 2) : ((g - 32) >> 2);
  float m_ = decf(mx[dst * 8 + h]);
  float alpha = __expf(logits[(size_t)e * 8 + h] - m_) / den[dst * 8 + h];
  if (g < 32) {
    float v[5];
#pragma unroll
    for (int n = 0; n < 5; n++) v[n] = __bfloat162float(v_buf[(size_t)e * 160 + g * 5 + n]);
    const float* rb = Rw + (size_t)e * 50 + l * 25;
    float R[5][5];
#pragma unroll
    for (int a = 0; a < 5; a++)
#pragma unroll
      for (int b = 0; b < 5; b++) R[a][b] = rb[a * 5 + b];
#pragma unroll
    for (int m = 0; m < 5; m++) {
      float o = R[0][m] * v[0] + R[1][m] * v[1] + R[2][m] * v[2] + R[3][m] * v[3] + R[4][m] * v[4];
      atomicAdd(&att[(size_t)dst * 160 + g * 5 + m], alpha * o);
    }
  } else {
    int j = g - 32;
    float v0 = __bfloat162float(v0_buf[(size_t)e * 32 + j]);
    atomicAdd(&att0[(size_t)dst * 32 + j], alpha * v0);
  }
}

// ---------------------------------------------------------------------------
// Kernel 4b (fallback): recompute v branch, REGISTER-ONLY.
// ---------------------------------------------------------------------------
__global__ __launch_bounds__(256) void edgeB_rec(
    const float* __restrict__ kvmixN, const float* __restrict__ kv0N,
    const float* __restrict__ Rw, const int* __restrict__ edge,
    const float* __restrict__ w_chunk, int e0,
    const float* __restrict__ logits, const unsigned* __restrict__ mx,
    const float* __restrict__ den,
    float* __restrict__ att, float* __restrict__ att0, int E) {
  const int g = threadIdx.x & 63;
  const int e = e0 + blockIdx.x * 4 + (threadIdx.x >> 6);
  const int src = edge[e], dst = edge[E + e];
  const int l = g & 1;
  const int h = (g < 32) ? (g >> 2) : ((g - 32) >> 2);
  float m_ = decf(mx[dst * 8 + h]);
  float alpha = __expf(logits[(size_t)e * 8 + h] - m_) / den[dst * 8 + h];
  const float* wa = w_chunk + (size_t)(e - e0) * 384;
  if (g < 32) {
    const float* rb = Rw + (size_t)e * 50 + l * 25;
    float R[5][5];
#pragma unroll
    for (int a = 0; a < 5; a++)
#pragma unroll
      for (int b = 0; b < 5; b++) R[a][b] = rb[a * 5 + b];
    float xr[5];
    {
      const float* xb = kvmixN + (size_t)src * 320 + 160 + g * 5;
      float x0 = xb[0], x1 = xb[1], x2 = xb[2], x3 = xb[3], x4 = xb[4];
#pragma unroll
      for (int m = 0; m < 5; m++)
        xr[m] = R[m][0] * x0 + R[m][1] * x1 + R[m][2] * x2 + R[m][3] * x3 + R[m][4] * x4;
    }
    int base = (32 + g) * 4;
    float w0_ = wa[base], w1_ = wa[base + 1], w2_ = wa[base + 2], w3_ = wa[base + 3];
    float wm = wa[352 + g];
    float y[5];
    y[0] = w3_ * xr[4] + w1_ * xr[0];
    y[1] = w2_ * xr[3] + w0_ * xr[1];
    y[2] = wm * xr[2];
    y[3] = w0_ * xr[3] - w2_ * xr[1];
    y[4] = w1_ * xr[4] - w3_ * xr[0];
#pragma unroll
    for (int m = 0; m < 5; m++) {
      float o = R[0][m] * y[0] + R[1][m] * y[1] + R[2][m] * y[2] + R[3][m] * y[3] + R[4][m] * y[4];
      atomicAdd(&att[(size_t)dst * 160 + g * 5 + m], alpha * o);
    }
  } else {
    int j = g - 32;
    float v0 = wa[288 + j] * kv0N[(size_t)src * 64 + 32 + j];
    atomicAdd(&att0[(size_t)dst * 32 + j], alpha * v0);
  }
}

// ---------------------------------------------------------------------------
// Kernel 5: per-node output projection, in place over d_out
// ---------------------------------------------------------------------------
__global__ __launch_bounds__(256) void node_kernel(
    const float* __restrict__ pW, const float* __restrict__ pW0,
    const float* __restrict__ pb0, float* __restrict__ out, int N) {
  __shared__ float sA[4][160];
  __shared__ float sA0[4][32];
  const int tid = threadIdx.x;
  const int wv = tid >> 6, w = tid & 63;
  const int n = blockIdx.x * 4 + wv;
  if (n < N) {
    for (int i = w; i < 160; i += 64) sA[wv][i] = out[(size_t)n * 160 + i];
    if (w < 32) sA0[wv][w] = out[(size_t)N * 160 + (size_t)n * 32 + w];
  }
  __syncthreads();
  if (n >= N) return;
  for (int i = w; i < 160; i += 64) {
    int o = i / 10, lm = i % 10, l = lm / 5, m = lm % 5;
    float a = 0.f;
    const float* wr = pW + l * 256 + o * 16;
#pragma unroll
    for (int c = 0; c < 16; c++) a += wr[c] * sA[wv][c * 10 + l * 5 + m];
    out[(size_t)n * 160 + i] = a;
  }
  if (w < 32) {
    float a = pb0[w];
    const float* wr = pW0 + w * 32;
#pragma unroll
    for (int c = 0; c < 32; c++) a += wr[c] * sA0[wv][c];
    out[(size_t)N * 160 + (size_t)n * 32 + w] = a;
  }
}

// ---------------------------------------------------------------------------
extern "C" void kernel_launch(void* const* d_in, const int* in_sizes, int n_in,
                              void* d_out, int out_size, void* d_ws, size_t ws_size,
                              hipStream_t stream) {
  const float* x_src  = (const float*)d_in[0];
  const float* x_tar  = (const float*)d_in[1];
  const float* x_src0 = (const float*)d_in[2];
  const float* x_tar0 = (const float*)d_in[3];
  const float* Rw     = (const float*)d_in[4];
  const float* ef     = (const float*)d_in[5];
  const int*   edge   = (const int*)d_in[6];
  const float* r_W1 = (const float*)d_in[10];
  const float* r_b1 = (const float*)d_in[11];
  const float* r_g1 = (const float*)d_in[12];
  const float* r_be1 = (const float*)d_in[13];
  const float* r_W2 = (const float*)d_in[14];
  const float* r_b2 = (const float*)d_in[15];
  const float* r_g2 = (const float*)d_in[16];
  const float* r_be2 = (const float*)d_in[17];
  const float* r_W3 = (const float*)d_in[18];
  const float* r_b3 = (const float*)d_in[19];
  const float* qW  = (const float*)d_in[20];
  const float* qW0 = (const float*)d_in[21];
  const float* qb0 = (const float*)d_in[22];
  const float* kvW  = (const float*)d_in[23];
  const float* kvW0 = (const float*)d_in[24];
  const float* kvb0 = (const float*)d_in[25];
  const float* qng  = (const float*)d_in[26];
  const float* qng0 = (const float*)d_in[27];
  const float* kng  = (const float*)d_in[28];
  const float* kng0 = (const float*)d_in[29];
  const float* pW  = (const float*)d_in[30];
  const float* pW0 = (const float*)d_in[31];
  const float* pb0 = (const float*)d_in[32];

  const int N = in_sizes[0] / 160;   // 10000
  const int E = in_sizes[4] / 50;    // 160000
  float* out = (float*)d_out;

  char* ws = (char*)d_ws;
  size_t off = 0;
  unsigned short* W1T = (unsigned short*)(ws + off); off += 128 * 32 * 2;
  unsigned short* W2T = (unsigned short*)(ws + off); off += 128 * 128 * 2;
  unsigned short* W3T = (unsigned short*)(ws + off); off += 384 * 128 * 2;
  float* logits = (float*)(ws + off); off += (size_t)E * 8 * 4;
  size_t zoff = off;
  unsigned* mxb = (unsigned*)(ws + off); off += (size_t)N * 8 * 4;
  float* den = (float*)(ws + off); off += (size_t)N * 8 * 4;
  size_t zend = off;
  float* qmixN  = (float*)(ws + off); off += (size_t)N * 160 * 4;
  float* q0N    = (float*)(ws + off); off += (size_t)N * 32 * 4;
  float* kvmixN = (float*)(ws + off); off += (size_t)N * 320 * 4;
  float* kv0N   = (float*)(ws + off); off += (size_t)N * 64 * 4;

  if (ws_size <= off + 128 * 384 * 4) return;
  size_t avail = ws_size - off;
  const size_t vsz = (size_t)E * 160 * 2 + (size_t)E * 32 * 2;
  bool fast = false;
  size_t CE;
  __hip_bfloat16 *vb = nullptr, *v0b = nullptr;
  if (avail >= vsz + (size_t)1024 * 384 * 4) {
    fast = true;
    vb  = (__hip_bfloat16*)(ws + off); off += (size_t)E * 160 * 2;
    v0b = (__hip_bfloat16*)(ws + off); off += (size_t)E * 32 * 2;
    CE = (ws_size - off) / (384 * 4);
  } else {
    CE = avail / (384 * 4);
  }
  if (CE > (size_t)E) CE = E;
  CE &= ~(size_t)127;
  if (CE == 0) return;
  float* w_chunk = (float*)(ws + off);

  hipMemsetAsync(ws + zoff, 0, zend - zoff, stream);
  hipMemsetAsync(d_out, 0, (size_t)out_size * 4, stream);

  prep_kernel<<<(69632 + 255) / 256, 256, 0, stream>>>(r_W1, r_W2, r_W3, W1T, W2T, W3T);
  nodeprep_kernel<<<(N + 3) / 4, 256, 0, stream>>>(
      x_tar, x_tar0, x_src, x_src0, qW, qW0, qb0, qng0, kvW, kvW0, kvb0,
      qmixN, q0N, kvmixN, kv0N, N);

  for (int e0 = 0; e0 < E; e0 += (int)CE) {
    int cnt = E - e0 < (int)CE ? E - e0 : (int)CE;
    radial_mfma<<<(cnt + 127) / 128, 256, 0, stream>>>(
        ef, W1T, W2T, W3T, r_b1, r_g1, r_be1, r_b2, r_g2, r_be2, r_b3, w_chunk, e0, E);
    if (fast)
      edgeA_kernel<1><<<cnt / 4, 256, 0, stream>>>(qmixN, q0N, kvmixN, kv0N, Rw, edge,
                                                   w_chunk, e0, qng, kng, kng0,
                                                   vb, v0b, logits, mxb, E);
    else
      edgeA_kernel<0><<<cnt / 4, 256, 0, stream>>>(qmixN, q0N, kvmixN, kv0N, Rw, edge,
                                                   w_chunk, e0, qng, kng, kng0,
                                                   vb, v0b, logits, mxb, E);
  }
  edge2_kernel<<<(E * 8 + 255) / 256, 256, 0, stream>>>(edge, logits, mxb, den, E);
  float* att  = out;
  float* att0 = out + (size_t)N * 160;
  if (fast) {
    edgeB_light<<<E / 4, 256, 0, stream>>>(Rw, edge, vb, v0b, logits, mxb, den, att, att0, E);
  } else {
    for (int e0 = 0; e0 < E; e0 += (int)CE) {
      int cnt = E - e0 < (int)CE ? E - e0 : (int)CE;
      radial_mfma<<<(cnt + 127) / 128, 256, 0, stream>>>(
          ef, W1T, W2T, W3T, r_b1, r_g1, r_be1, r_b2, r_g2, r_be2, r_b3, w_chunk, e0, E);
      edgeB_rec<<<cnt / 4, 256, 0, stream>>>(kvmixN, kv0N, Rw, edge, w_chunk, e0,
                                             logits, mxb, den, att, att0, E);
    }
  }
  node_kernel<<<(N + 3) / 4, 256, 0, stream>>>(pW, pW0, pb0, out, N);
}

// Round 6
// 494.676 us; speedup vs baseline: 1.6016x; 1.6016x over previous
//
#include <hip/hip_runtime.h>
#include <hip/hip_bf16.h>
#include <math.h>

// N=10000, E=160000, C=16, C0=32, L=2, M=5, H=8, R_IN=32, R_HID=128, REQ=384

typedef short bf16x8 __attribute__((ext_vector_type(8)));
typedef float f32x4 __attribute__((ext_vector_type(4)));

__device__ __forceinline__ float waveSum(float v) {
#pragma unroll
  for (int m = 1; m < 64; m <<= 1) v += __shfl_xor(v, m, 64);
  return v;
}
__device__ __forceinline__ unsigned encf(float f) {
  unsigned u = __float_as_uint(f);
  return (u & 0x80000000u) ? ~u : (u | 0x80000000u);
}
__device__ __forceinline__ float decf(unsigned u) {
  return (u & 0x80000000u) ? __uint_as_float(u & 0x7FFFFFFFu) : __uint_as_float(~u);
}
__device__ __forceinline__ unsigned short f2bu(float f) {
  __hip_bfloat16 h = __float2bfloat16(f);
  unsigned short u;
  __builtin_memcpy(&u, &h, 2);
  return u;
}

// ---------------------------------------------------------------------------
// Prep: transpose radial weights to bf16 [n][k] layout
// ---------------------------------------------------------------------------
__global__ __launch_bounds__(256) void prep_kernel(
    const float* __restrict__ W1, const float* __restrict__ W2,
    const float* __restrict__ W3,
    unsigned short* __restrict__ W1T, unsigned short* __restrict__ W2T,
    unsigned short* __restrict__ W3T) {
  int idx = blockIdx.x * 256 + threadIdx.x;
  if (idx < 128 * 32) {
    int n = idx >> 5, k = idx & 31;
    W1T[idx] = f2bu(W1[k * 128 + n]);
  }
  int i2 = idx - 128 * 32;
  if (i2 >= 0 && i2 < 128 * 128) {
    int n = i2 >> 7, k = i2 & 127;
    W2T[i2] = f2bu(W2[k * 128 + n]);
  }
  int i3 = idx - 128 * 32 - 128 * 128;
  if (i3 >= 0 && i3 < 384 * 128) {
    int n = i3 >> 7, k = i3 & 127;
    W3T[i3] = f2bu(W3[k * 384 + n]);
  }
}

// ---------------------------------------------------------------------------
// CSR build: count, scan (1 block), fill
// ---------------------------------------------------------------------------
__global__ __launch_bounds__(256) void count_kernel(const int* __restrict__ edge,
                                                    int* __restrict__ cnt, int E) {
  int e = blockIdx.x * 256 + threadIdx.x;
  if (e < E) atomicAdd(&cnt[edge[E + e]], 1);
}

__global__ __launch_bounds__(1024) void scan_kernel(const int* __restrict__ cnt,
                                                    int* __restrict__ rowstart, int N) {
  __shared__ int sp[1024];
  const int t = threadIdx.x;
  const int chunk = (N + 1023) >> 10;
  const int beg = t * chunk;
  const int end = min(beg + chunk, N);
  int s = 0;
  for (int i = beg; i < end; i++) s += cnt[i];
  sp[t] = s;
  __syncthreads();
  for (int off = 1; off < 1024; off <<= 1) {
    int tmp = (t >= off) ? sp[t - off] : 0;
    __syncthreads();
    sp[t] += tmp;
    __syncthreads();
  }
  int excl = sp[t] - s;
  int run = excl;
  for (int i = beg; i < end; i++) { rowstart[i] = run; run += cnt[i]; }
  if (t == 0) rowstart[N] = sp[1023];
}

__global__ __launch_bounds__(256) void fill_kernel(const int* __restrict__ edge,
                                                   const int* __restrict__ rowstart,
                                                   int* __restrict__ cursor,
                                                   int* __restrict__ csr, int E) {
  int e = blockIdx.x * 256 + threadIdx.x;
  if (e < E) {
    int d = edge[E + e];
    int p = atomicAdd(&cursor[d], 1);
    csr[rowstart[d] + p] = e;
  }
}

// ---------------------------------------------------------------------------
// Node prep: hoist channel-mix GEMMs from edges to nodes.
// ---------------------------------------------------------------------------
__global__ __launch_bounds__(256) void nodeprep_kernel(
    const float* __restrict__ xt, const float* __restrict__ xt0,
    const float* __restrict__ xs, const float* __restrict__ xs0,
    const float* __restrict__ qW, const float* __restrict__ qW0,
    const float* __restrict__ qb0, const float* __restrict__ qng0,
    const float* __restrict__ kvW, const float* __restrict__ kvW0,
    const float* __restrict__ kvb0,
    float* __restrict__ qmixN, float* __restrict__ q0N,
    float* __restrict__ kvmixN, float* __restrict__ kv0N, int N) {
  __shared__ float sXT[4][160];
  __shared__ float sXS[4][160];
  __shared__ float sX0T[4][32];
  __shared__ float sX0S[4][32];
  const int tid = threadIdx.x, wv = tid >> 6, w = tid & 63;
  const int n = blockIdx.x * 4 + wv;
  if (n < N) {
    for (int i = w; i < 160; i += 64) {
      sXT[wv][i] = xt[(size_t)n * 160 + i];
      sXS[wv][i] = xs[(size_t)n * 160 + i];
    }
    if (w < 32) { sX0T[wv][w] = xt0[n * 32 + w]; sX0S[wv][w] = xs0[n * 32 + w]; }
  }
  __syncthreads();
  if (n >= N) return;
  for (int i = w; i < 160; i += 64) {
    int o = i / 10, lm = i % 10, l = lm / 5;
    const float4* wr = (const float4*)(qW + l * 256 + o * 16);
    float a = 0.f;
#pragma unroll
    for (int c4 = 0; c4 < 4; c4++) {
      float4 ww = wr[c4];
      a += ww.x * sXT[wv][(c4 * 4 + 0) * 10 + lm] + ww.y * sXT[wv][(c4 * 4 + 1) * 10 + lm]
         + ww.z * sXT[wv][(c4 * 4 + 2) * 10 + lm] + ww.w * sXT[wv][(c4 * 4 + 3) * 10 + lm];
    }
    qmixN[(size_t)n * 160 + i] = a;
  }
  for (int i = w; i < 320; i += 64) {
    int o = i / 10, lm = i % 10, l = lm / 5;
    const float4* wr = (const float4*)(kvW + l * 512 + o * 16);
    float a = 0.f;
#pragma unroll
    for (int c4 = 0; c4 < 4; c4++) {
      float4 ww = wr[c4];
      a += ww.x * sXS[wv][(c4 * 4 + 0) * 10 + lm] + ww.y * sXS[wv][(c4 * 4 + 1) * 10 + lm]
         + ww.z * sXS[wv][(c4 * 4 + 2) * 10 + lm] + ww.w * sXS[wv][(c4 * 4 + 3) * 10 + lm];
    }
    kvmixN[(size_t)n * 320 + i] = a;
  }
  {
    float a = 0.f;
    if (w < 32) {
      a = qb0[w];
      const float4* wr = (const float4*)(qW0 + w * 32);
#pragma unroll
      for (int c4 = 0; c4 < 8; c4++) {
        float4 ww = wr[c4];
        a += ww.x * sX0T[wv][c4 * 4] + ww.y * sX0T[wv][c4 * 4 + 1]
           + ww.z * sX0T[wv][c4 * 4 + 2] + ww.w * sX0T[wv][c4 * 4 + 3];
      }
    }
    float vv = (w < 32) ? a : 0.f;
    float s1 = waveSum(vv), s2 = waveSum(vv * vv);
    float mu = s1 / 32.f, var = s2 / 32.f - mu * mu;
    if (w < 32) q0N[(size_t)n * 32 + w] = (a - mu) * rsqrtf(var + 1e-5f) * qng0[w];
  }
  {
    float a = kvb0[w];
    const float4* wr = (const float4*)(kvW0 + w * 32);
#pragma unroll
    for (int c4 = 0; c4 < 8; c4++) {
      float4 ww = wr[c4];
      a += ww.x * sX0S[wv][c4 * 4] + ww.y * sX0S[wv][c4 * 4 + 1]
         + ww.z * sX0S[wv][c4 * 4 + 2] + ww.w * sX0S[wv][c4 * 4 + 3];
    }
    kv0N[(size_t)n * 64 + w] = a;
  }
}

// ---------------------------------------------------------------------------
// Kernel 1: MFMA radial MLP (unchanged)
// ---------------------------------------------------------------------------
__global__ __launch_bounds__(256) void radial_mfma(
    const float* __restrict__ ef,
    const unsigned short* __restrict__ W1T, const unsigned short* __restrict__ W2T,
    const unsigned short* __restrict__ W3T,
    const float* __restrict__ b1, const float* __restrict__ g1, const float* __restrict__ be1,
    const float* __restrict__ b2, const float* __restrict__ g2, const float* __restrict__ be2,
    const float* __restrict__ b3,
    float* __restrict__ w_chunk, int e0, int E) {
  __shared__ unsigned short sA[128 * 128];
  __shared__ unsigned short sW[128 * 128];
  const int tid = threadIdx.x;
  const int lane = tid & 63, wid = tid >> 6;
  const int eb = blockIdx.x * 128;
  const int colq = lane & 15, rowq = lane >> 4;

  float b1v[8], g1v[8], be1v[8], b2v[8], g2v[8], be2v[8];
#pragma unroll
  for (int nt = 0; nt < 8; nt++) {
    int c = nt * 16 + colq;
    b1v[nt] = b1[c]; g1v[nt] = g1[c]; be1v[nt] = be1[c];
    b2v[nt] = b2[c]; g2v[nt] = g2[c]; be2v[nt] = be2[c];
  }

  for (int idx = tid; idx < 1024; idx += 256) {
    int e = idx >> 3, k4 = idx & 7;
    int ee = e0 + eb + e; if (ee >= E) ee = E - 1;
    float4 v = *(const float4*)&ef[(size_t)ee * 32 + k4 * 4];
    ushort4 uu = make_ushort4(f2bu(v.x), f2bu(v.y), f2bu(v.z), f2bu(v.w));
    unsigned bo = (unsigned)e * 256 + (((unsigned)k4 * 8) ^ ((e & 7) << 4));
    *(ushort4*)((char*)sA + bo) = uu;
  }
  for (int idx = tid; idx < 512; idx += 256) {
    int n = idx >> 2, j = idx & 3;
    uint4 v = *(const uint4*)&W1T[n * 32 + j * 8];
    unsigned bo = (unsigned)n * 256 + (((unsigned)j * 16) ^ ((n & 7) << 4));
    *(uint4*)((char*)sW + bo) = v;
  }
  __syncthreads();

  f32x4 zz = {0.f, 0.f, 0.f, 0.f};
  f32x4 acc[2][8];
#pragma unroll
  for (int mt = 0; mt < 2; mt++)
#pragma unroll
    for (int nt = 0; nt < 8; nt++) acc[mt][nt] = zz;

  {
    bf16x8 af[2];
#pragma unroll
    for (int mt = 0; mt < 2; mt++) {
      int row = wid * 32 + mt * 16 + colq;
      unsigned bo = (unsigned)row * 256 + (((unsigned)rowq * 16) ^ ((row & 7) << 4));
      af[mt] = *(const bf16x8*)((const char*)sA + bo);
    }
#pragma unroll
    for (int nt = 0; nt < 8; nt++) {
      int n = nt * 16 + colq;
      unsigned bo = (unsigned)n * 256 + (((unsigned)rowq * 16) ^ ((n & 7) << 4));
      bf16x8 bfv = *(const bf16x8*)((const char*)sW + bo);
#pragma unroll
      for (int mt = 0; mt < 2; mt++)
        acc[mt][nt] = __builtin_amdgcn_mfma_f32_16x16x32_bf16(af[mt], bfv, acc[mt][nt], 0, 0, 0);
    }
  }
  __syncthreads();

#pragma unroll
  for (int mt = 0; mt < 2; mt++) {
#pragma unroll
    for (int r = 0; r < 4; r++) {
      float s1 = 0.f, s2 = 0.f;
#pragma unroll
      for (int nt = 0; nt < 8; nt++) {
        float v = acc[mt][nt][r] + b1v[nt];
        s1 += v; s2 += v * v;
      }
#pragma unroll
      for (int off = 1; off < 16; off <<= 1) { s1 += __shfl_xor(s1, off, 64); s2 += __shfl_xor(s2, off, 64); }
      float mu = s1 * (1.f / 128.f);
      float rs = rsqrtf(s2 * (1.f / 128.f) - mu * mu + 1e-5f);
      int row = wid * 32 + mt * 16 + rowq * 4 + r;
      unsigned rbase = (unsigned)row * 256;
      unsigned swz = (row & 7) << 4;
#pragma unroll
      for (int nt = 0; nt < 8; nt++) {
        float v = (acc[mt][nt][r] + b1v[nt] - mu) * rs * g1v[nt] + be1v[nt];
        v = v / (1.f + __expf(-v));
        *(unsigned short*)((char*)sA + rbase + ((((unsigned)(nt * 16 + colq)) * 2) ^ swz)) = f2bu(v);
      }
    }
  }
  for (int idx = tid; idx < 2048; idx += 256) {
    int n = idx >> 4, j = idx & 15;
    uint4 v = *(const uint4*)&W2T[n * 128 + j * 8];
    unsigned bo = (unsigned)n * 256 + (((unsigned)j * 16) ^ ((n & 7) << 4));
    *(uint4*)((char*)sW + bo) = v;
  }
  __syncthreads();

#pragma unroll
  for (int mt = 0; mt < 2; mt++)
#pragma unroll
    for (int nt = 0; nt < 8; nt++) acc[mt][nt] = zz;
#pragma unroll
  for (int ks = 0; ks < 4; ks++) {
    bf16x8 af[2];
#pragma unroll
    for (int mt = 0; mt < 2; mt++) {
      int row = wid * 32 + mt * 16 + colq;
      unsigned bo = (unsigned)row * 256 + (((unsigned)(ks * 64 + rowq * 16)) ^ ((row & 7) << 4));
      af[mt] = *(const bf16x8*)((const char*)sA + bo);
    }
#pragma unroll
    for (int nt = 0; nt < 8; nt++) {
      int n = nt * 16 + colq;
      unsigned bo = (unsigned)n * 256 + (((unsigned)(ks * 64 + rowq * 16)) ^ ((n & 7) << 4));
      bf16x8 bfv = *(const bf16x8*)((const char*)sW + bo);
#pragma unroll
      for (int mt = 0; mt < 2; mt++)
        acc[mt][nt] = __builtin_amdgcn_mfma_f32_16x16x32_bf16(af[mt], bfv, acc[mt][nt], 0, 0, 0);
    }
  }
  __syncthreads();

#pragma unroll
  for (int mt = 0; mt < 2; mt++) {
#pragma unroll
    for (int r = 0; r < 4; r++) {
      float s1 = 0.f, s2 = 0.f;
#pragma unroll
      for (int nt = 0; nt < 8; nt++) {
        float v = acc[mt][nt][r] + b2v[nt];
        s1 += v; s2 += v * v;
      }
#pragma unroll
      for (int off = 1; off < 16; off <<= 1) { s1 += __shfl_xor(s1, off, 64); s2 += __shfl_xor(s2, off, 64); }
      float mu = s1 * (1.f / 128.f);
      float rs = rsqrtf(s2 * (1.f / 128.f) - mu * mu + 1e-5f);
      int row = wid * 32 + mt * 16 + rowq * 4 + r;
      unsigned rbase = (unsigned)row * 256;
      unsigned swz = (row & 7) << 4;
#pragma unroll
      for (int nt = 0; nt < 8; nt++) {
        float v = (acc[mt][nt][r] + b2v[nt] - mu) * rs * g2v[nt] + be2v[nt];
        v = v / (1.f + __expf(-v));
        *(unsigned short*)((char*)sA + rbase + ((((unsigned)(nt * 16 + colq)) * 2) ^ swz)) = f2bu(v);
      }
    }
  }

  for (int cc = 0; cc < 3; cc++) {
    if (cc > 0) __syncthreads();
    for (int idx = tid; idx < 2048; idx += 256) {
      int n = idx >> 4, j = idx & 15;
      uint4 v = *(const uint4*)&W3T[(size_t)(cc * 128 + n) * 128 + j * 8];
      unsigned bo = (unsigned)n * 256 + (((unsigned)j * 16) ^ ((n & 7) << 4));
      *(uint4*)((char*)sW + bo) = v;
    }
    __syncthreads();
    f32x4 a3[2][8];
#pragma unroll
    for (int mt = 0; mt < 2; mt++)
#pragma unroll
      for (int nt = 0; nt < 8; nt++) a3[mt][nt] = zz;
#pragma unroll
    for (int ks = 0; ks < 4; ks++) {
      bf16x8 af[2];
#pragma unroll
      for (int mt = 0; mt < 2; mt++) {
        int row = wid * 32 + mt * 16 + colq;
        unsigned bo = (unsigned)row * 256 + (((unsigned)(ks * 64 + rowq * 16)) ^ ((row & 7) << 4));
        af[mt] = *(const bf16x8*)((const char*)sA + bo);
      }
#pragma unroll
      for (int nt = 0; nt < 8; nt++) {
        int n = nt * 16 + colq;
        unsigned bo = (unsigned)n * 256 + (((unsigned)(ks * 64 + rowq * 16)) ^ ((n & 7) << 4));
        bf16x8 bfv = *(const bf16x8*)((const char*)sW + bo);
#pragma unroll
        for (int mt = 0; mt < 2; mt++)
          a3[mt][nt] = __builtin_amdgcn_mfma_f32_16x16x32_bf16(af[mt], bfv, a3[mt][nt], 0, 0, 0);
      }
    }
#pragma unroll
    for (int nt = 0; nt < 8; nt++) {
      int col = cc * 128 + nt * 16 + colq;
      float b3v = b3[col];
#pragma unroll
      for (int mt = 0; mt < 2; mt++) {
#pragma unroll
        for (int r = 0; r < 4; r++) {
          int row_e = eb + wid * 32 + mt * 16 + rowq * 4 + r;
          w_chunk[(size_t)row_e * 384 + col] = a3[mt][nt][r] + b3v;
        }
      }
    }
  }
}

// ---------------------------------------------------------------------------
// Kernel 2: per-edge rotate+conv+norm+logits, REGISTER-ONLY.
// STOREV=1 (fast path): write logits + v/v0, no atomics at all.
// STOREV=0 (fallback): also atomicMax segment max.
// ---------------------------------------------------------------------------
template <int STOREV>
__global__ __launch_bounds__(256) void edgeA_kernel(
    const float* __restrict__ qmixN, const float* __restrict__ q0N,
    const float* __restrict__ kvmixN, const float* __restrict__ kv0N,
    const float* __restrict__ Rw, const int* __restrict__ edge,
    const float* __restrict__ w_chunk, int e0,
    const float* __restrict__ qng, const float* __restrict__ kng,
    const float* __restrict__ kng0,
    __hip_bfloat16* __restrict__ v_buf, __hip_bfloat16* __restrict__ v0_buf,
    float* __restrict__ logits, unsigned* __restrict__ mx, int E) {
  const int g = threadIdx.x & 63;
  const int e = e0 + blockIdx.x * 4 + (threadIdx.x >> 6);
  const int src = edge[e], dst = edge[E + e];
  const int l = g & 1, cg = g >> 1;

  float R[5][5];
  {
    const float* rb = Rw + (size_t)e * 50 + l * 25;
#pragma unroll
    for (int m = 0; m < 5; m++)
#pragma unroll
      for (int n = 0; n < 5; n++) R[m][n] = rb[m * 5 + n];
  }
  float xr[5];
  {
    const float* xb = kvmixN + (size_t)src * 320 + g * 5;
    float x0 = xb[0], x1 = xb[1], x2 = xb[2], x3 = xb[3], x4 = xb[4];
#pragma unroll
    for (int m = 0; m < 5; m++)
      xr[m] = R[m][0] * x0 + R[m][1] * x1 + R[m][2] * x2 + R[m][3] * x3 + R[m][4] * x4;
  }
  const float* wa = w_chunk + (size_t)(e - e0) * 384;
  float w0_ = wa[4 * g], w1_ = wa[4 * g + 1], w2_ = wa[4 * g + 2], w3_ = wa[4 * g + 3];
  float wm = wa[320 + g];
  float y[5];
  y[0] = w3_ * xr[4] + w1_ * xr[0];
  y[1] = w2_ * xr[3] + w0_ * xr[1];
  y[2] = wm * xr[2];
  y[3] = w0_ * xr[3] - w2_ * xr[1];
  y[4] = w1_ * xr[4] - w3_ * xr[0];
  float y0 = wa[256 + g] * kv0N[(size_t)src * 64 + g];

  float p = 0.f;
  if (g < 32) p = y[0] * y[0] + y[1] * y[1] + y[2] * y[2] + y[3] * y[3] + y[4] * y[4];
  float rmsk = rsqrtf(waveSum(p) * (1.f / 160.f) + 1e-5f);
  float kngc = (g < 32) ? kng[cg] : 0.f;
  float yk[5];
#pragma unroll
  for (int m = 0; m < 5; m++) yk[m] = y[m] * rmsk * kngc;
  float k0v = (g < 32) ? y0 : 0.f;
  float s1 = waveSum(k0v), s2 = waveSum(k0v * k0v);
  float mu = s1 * (1.f / 32.f), var = s2 * (1.f / 32.f) - mu * mu;
  float k0n = (k0v - mu) * rsqrtf(var + 1e-5f) * ((g < 32) ? kng0[g] : 0.f);

  float qn[5];
  float q0 = 0.f;
  {
    float qx0 = 0.f, qx1 = 0.f, qx2 = 0.f, qx3 = 0.f, qx4 = 0.f;
    if (g < 32) {
      const float* qb = qmixN + (size_t)dst * 160 + g * 5;
      qx0 = qb[0]; qx1 = qb[1]; qx2 = qb[2]; qx3 = qb[3]; qx4 = qb[4];
      q0 = q0N[(size_t)dst * 32 + g];
    }
    float qr[5];
#pragma unroll
    for (int m = 0; m < 5; m++)
      qr[m] = R[m][0] * qx0 + R[m][1] * qx1 + R[m][2] * qx2 + R[m][3] * qx3 + R[m][4] * qx4;
    float pq = qr[0] * qr[0] + qr[1] * qr[1] + qr[2] * qr[2] + qr[3] * qr[3] + qr[4] * qr[4];
    float rmsq = rsqrtf(waveSum(pq) * (1.f / 160.f) + 1e-5f);
    float qngc = (g < 32) ? qng[cg] : 0.f;
#pragma unroll
    for (int m = 0; m < 5; m++) qn[m] = qr[m] * rmsq * qngc;
  }

  float part = qn[0] * yk[0] + qn[1] * yk[1] + qn[2] * yk[2] + qn[3] * yk[3] + qn[4] * yk[4]
             + q0 * k0n;
  part += __shfl_xor(part, 1, 64);
  part += __shfl_xor(part, 2, 64);
  if (g < 32 && (g & 3) == 0) {
    int h = g >> 2;
    float lg = part * 0.70710678118654752f;
    logits[(size_t)e * 8 + h] = lg;
    if (!STOREV) atomicMax(&mx[dst * 8 + h], encf(lg));
  }
  if (STOREV && g >= 32) {
    int j = g - 32;
#pragma unroll
    for (int m = 0; m < 5; m++)
      v_buf[(size_t)e * 160 + j * 5 + m] = __float2bfloat16(y[m]);
    v0_buf[(size_t)e * 32 + j] = __float2bfloat16(y0);
  }
}

// ---------------------------------------------------------------------------
// Kernel 3 (fallback only): denominator
// ---------------------------------------------------------------------------
__global__ __launch_bounds__(256) void edge2_kernel(
    const int* __restrict__ edge, const float* __restrict__ logits,
    const unsigned* __restrict__ mx, float* __restrict__ den, int E) {
  int idx = blockIdx.x * 256 + threadIdx.x;
  if (idx >= E * 8) return;
  int e = idx >> 3, h = idx & 7;
  int dst = edge[E + e];
  float m = decf(mx[dst * 8 + h]);
  atomicAdd(&den[dst * 8 + h], __expf(logits[idx] - m));
}

// ---------------------------------------------------------------------------
// Kernel 4 (fast): per-NODE gather: softmax over incident edges + alpha*v
// inverse-rotation, accumulate in registers, plain stores.  NO ATOMICS.
// Wave per node; lane g<32 owns kv-group (c,l) (5 m-values); g>=32 owns att0[j].
// ---------------------------------------------------------------------------
__global__ __launch_bounds__(256) void nodegather_kernel(
    const float* __restrict__ Rw, const int* __restrict__ csr,
    const int* __restrict__ rowstart,
    const __hip_bfloat16* __restrict__ v_buf, const __hip_bfloat16* __restrict__ v0_buf,
    const float* __restrict__ logits,
    float* __restrict__ att, float* __restrict__ att0, int N) {
  const int g = threadIdx.x & 63;
  const int n = blockIdx.x * 4 + (threadIdx.x >> 6);
  if (n >= N) return;
  const int row = rowstart[n];
  const int deg = rowstart[n + 1] - row;
  const int l = g & 1;
  const int h = (g < 32) ? (g >> 2) : ((g - 32) >> 2);

  if (deg == 0) {
    if (g < 32) {
#pragma unroll
      for (int m = 0; m < 5; m++) att[(size_t)n * 160 + g * 5 + m] = 0.f;
    } else {
      att0[(size_t)n * 32 + (g - 32)] = 0.f;
    }
    return;
  }

  // pass 1: per-head max
  float mxh = -3.402823466e38f;
  for (int k = 0; k < deg; k++) {
    int e = csr[row + k];
    mxh = fmaxf(mxh, logits[(size_t)e * 8 + h]);
  }
  // pass 2: denominator
  float dn = 0.f;
  for (int k = 0; k < deg; k++) {
    int e = csr[row + k];
    dn += __expf(logits[(size_t)e * 8 + h] - mxh);
  }
  float inv = 1.f / dn;

  // main pass: accumulate
  float acc[5] = {0.f, 0.f, 0.f, 0.f, 0.f};
  float acc0 = 0.f;
  for (int k = 0; k < deg; k++) {
    int e = csr[row + k];
    float alpha = __expf(logits[(size_t)e * 8 + h] - mxh) * inv;
    if (g < 32) {
      const __hip_bfloat16* vb = v_buf + (size_t)e * 160 + g * 5;
      float v0_ = __bfloat162float(vb[0]);
      float v1_ = __bfloat162float(vb[1]);
      float v2_ = __bfloat162float(vb[2]);
      float v3_ = __bfloat162float(vb[3]);
      float v4_ = __bfloat162float(vb[4]);
      const float* rb = Rw + (size_t)e * 50 + l * 25;
#pragma unroll
      for (int m = 0; m < 5; m++) {
        float o = rb[m] * v0_ + rb[5 + m] * v1_ + rb[10 + m] * v2_ +
                  rb[15 + m] * v3_ + rb[20 + m] * v4_;
        acc[m] += alpha * o;
      }
    } else {
      acc0 += alpha * __bfloat162float(v0_buf[(size_t)e * 32 + (g - 32)]);
    }
  }
  if (g < 32) {
#pragma unroll
    for (int m = 0; m < 5; m++) att[(size_t)n * 160 + g * 5 + m] = acc[m];
  } else {
    att0[(size_t)n * 32 + (g - 32)] = acc0;
  }
}

// ---------------------------------------------------------------------------
// Kernel 4b (fallback): recompute v branch, atomic scatter (old path)
// ---------------------------------------------------------------------------
__global__ __launch_bounds__(256) void edgeB_rec(
    const float* __restrict__ kvmixN, const float* __restrict__ kv0N,
    const float* __restrict__ Rw, const int* __restrict__ edge,
    const float* __restrict__ w_chunk, int e0,
    const float* __restrict__ logits, const unsigned* __restrict__ mx,
    const float* __restrict__ den,
    float* __restrict__ att, float* __restrict__ att0, int E) {
  const int g = threadIdx.x & 63;
  const int e = e0 + blockIdx.x * 4 + (threadIdx.x >> 6);
  const int src = edge[e], dst = edge[E + e];
  const int l = g & 1;
  const int h = (g < 32) ? (g >> 2) : ((g - 32) >> 2);
  float m_ = decf(mx[dst * 8 + h]);
  float alpha = __expf(logits[(size_t)e * 8 + h] - m_) / den[dst * 8 + h];
  const float* wa = w_chunk + (size_t)(e - e0) * 384;
  if (g < 32) {
    const float* rb = Rw + (size_t)e * 50 + l * 25;
    float R[5][5];
#pragma unroll
    for (int a = 0; a < 5; a++)
#pragma unroll
      for (int b = 0; b < 5; b++) R[a][b] = rb[a * 5 + b];
    float xr[5];
    {
      const float* xb = kvmixN + (size_t)src * 320 + 160 + g * 5;
      float x0 = xb[0], x1 = xb[1], x2 = xb[2], x3 = xb[3], x4 = xb[4];
#pragma unroll
      for (int m = 0; m < 5; m++)
        xr[m] = R[m][0] * x0 + R[m][1] * x1 + R[m][2] * x2 + R[m][3] * x3 + R[m][4] * x4;
    }
    int base = (32 + g) * 4;
    float w0_ = wa[base], w1_ = wa[base + 1], w2_ = wa[base + 2], w3_ = wa[base + 3];
    float wm = wa[352 + g];
    float y[5];
    y[0] = w3_ * xr[4] + w1_ * xr[0];
    y[1] = w2_ * xr[3] + w0_ * xr[1];
    y[2] = wm * xr[2];
    y[3] = w0_ * xr[3] - w2_ * xr[1];
    y[4] = w1_ * xr[4] - w3_ * xr[0];
#pragma unroll
    for (int m = 0; m < 5; m++) {
      float o = R[0][m] * y[0] + R[1][m] * y[1] + R[2][m] * y[2] + R[3][m] * y[3] + R[4][m] * y[4];
      atomicAdd(&att[(size_t)dst * 160 + g * 5 + m], alpha * o);
    }
  } else {
    int j = g - 32;
    float v0 = wa[288 + j] * kv0N[(size_t)src * 64 + 32 + j];
    atomicAdd(&att0[(size_t)dst * 32 + j], alpha * v0);
  }
}

// ---------------------------------------------------------------------------
// Kernel 5: per-node output projection, in place over d_out
// ---------------------------------------------------------------------------
__global__ __launch_bounds__(256) void node_kernel(
    const float* __restrict__ pW, const float* __restrict__ pW0,
    const float* __restrict__ pb0, float* __restrict__ out, int N) {
  __shared__ float sA[4][160];
  __shared__ float sA0[4][32];
  const int tid = threadIdx.x;
  const int wv = tid >> 6, w = tid & 63;
  const int n = blockIdx.x * 4 + wv;
  if (n < N) {
    for (int i = w; i < 160; i += 64) sA[wv][i] = out[(size_t)n * 160 + i];
    if (w < 32) sA0[wv][w] = out[(size_t)N * 160 + (size_t)n * 32 + w];
  }
  __syncthreads();
  if (n >= N) return;
  for (int i = w; i < 160; i += 64) {
    int o = i / 10, lm = i % 10, l = lm / 5, m = lm % 5;
    float a = 0.f;
    const float* wr = pW + l * 256 + o * 16;
#pragma unroll
    for (int c = 0; c < 16; c++) a += wr[c] * sA[wv][c * 10 + l * 5 + m];
    out[(size_t)n * 160 + i] = a;
  }
  if (w < 32) {
    float a = pb0[w];
    const float* wr = pW0 + w * 32;
#pragma unroll
    for (int c = 0; c < 32; c++) a += wr[c] * sA0[wv][c];
    out[(size_t)N * 160 + (size_t)n * 32 + w] = a;
  }
}

// ---------------------------------------------------------------------------
extern "C" void kernel_launch(void* const* d_in, const int* in_sizes, int n_in,
                              void* d_out, int out_size, void* d_ws, size_t ws_size,
                              hipStream_t stream) {
  const float* x_src  = (const float*)d_in[0];
  const float* x_tar  = (const float*)d_in[1];
  const float* x_src0 = (const float*)d_in[2];
  const float* x_tar0 = (const float*)d_in[3];
  const float* Rw     = (const float*)d_in[4];
  const float* ef     = (const float*)d_in[5];
  const int*   edge   = (const int*)d_in[6];
  const float* r_W1 = (const float*)d_in[10];
  const float* r_b1 = (const float*)d_in[11];
  const float* r_g1 = (const float*)d_in[12];
  const float* r_be1 = (const float*)d_in[13];
  const float* r_W2 = (const float*)d_in[14];
  const float* r_b2 = (const float*)d_in[15];
  const float* r_g2 = (const float*)d_in[16];
  const float* r_be2 = (const float*)d_in[17];
  const float* r_W3 = (const float*)d_in[18];
  const float* r_b3 = (const float*)d_in[19];
  const float* qW  = (const float*)d_in[20];
  const float* qW0 = (const float*)d_in[21];
  const float* qb0 = (const float*)d_in[22];
  const float* kvW  = (const float*)d_in[23];
  const float* kvW0 = (const float*)d_in[24];
  const float* kvb0 = (const float*)d_in[25];
  const float* qng  = (const float*)d_in[26];
  const float* qng0 = (const float*)d_in[27];
  const float* kng  = (const float*)d_in[28];
  const float* kng0 = (const float*)d_in[29];
  const float* pW  = (const float*)d_in[30];
  const float* pW0 = (const float*)d_in[31];
  const float* pb0 = (const float*)d_in[32];

  const int N = in_sizes[0] / 160;   // 10000
  const int E = in_sizes[4] / 50;    // 160000
  float* out = (float*)d_out;

  char* ws = (char*)d_ws;
  size_t off = 0;
  unsigned short* W1T = (unsigned short*)(ws + off); off += 128 * 32 * 2;
  unsigned short* W2T = (unsigned short*)(ws + off); off += 128 * 128 * 2;
  unsigned short* W3T = (unsigned short*)(ws + off); off += 384 * 128 * 2;
  float* logits = (float*)(ws + off); off += (size_t)E * 8 * 4;
  int* rowstart = (int*)(ws + off); off += (size_t)(N + 1) * 4;
  int* csr      = (int*)(ws + off); off += (size_t)E * 4;
  size_t zoff = off;
  int* cnt    = (int*)(ws + off); off += (size_t)N * 4;
  int* cursor = (int*)(ws + off); off += (size_t)N * 4;
  unsigned* mxb = (unsigned*)(ws + off); off += (size_t)N * 8 * 4;
  float* den = (float*)(ws + off); off += (size_t)N * 8 * 4;
  size_t zend = off;
  float* qmixN  = (float*)(ws + off); off += (size_t)N * 160 * 4;
  float* q0N    = (float*)(ws + off); off += (size_t)N * 32 * 4;
  float* kvmixN = (float*)(ws + off); off += (size_t)N * 320 * 4;
  float* kv0N   = (float*)(ws + off); off += (size_t)N * 64 * 4;

  if (ws_size <= off + 128 * 384 * 4) return;
  size_t avail = ws_size - off;
  const size_t vsz = (size_t)E * 160 * 2 + (size_t)E * 32 * 2;
  bool fast = false;
  size_t CE;
  __hip_bfloat16 *vb = nullptr, *v0b = nullptr;
  if (avail >= vsz + (size_t)1024 * 384 * 4) {
    fast = true;
    vb  = (__hip_bfloat16*)(ws + off); off += (size_t)E * 160 * 2;
    v0b = (__hip_bfloat16*)(ws + off); off += (size_t)E * 32 * 2;
    CE = (ws_size - off) / (384 * 4);
  } else {
    CE = avail / (384 * 4);
  }
  if (CE > (size_t)E) CE = E;
  CE &= ~(size_t)127;
  if (CE == 0) return;
  float* w_chunk = (float*)(ws + off);

  hipMemsetAsync(ws + zoff, 0, zend - zoff, stream);
  hipMemsetAsync(d_out, 0, (size_t)out_size * 4, stream);

  prep_kernel<<<(69632 + 255) / 256, 256, 0, stream>>>(r_W1, r_W2, r_W3, W1T, W2T, W3T);
  nodeprep_kernel<<<(N + 3) / 4, 256, 0, stream>>>(
      x_tar, x_tar0, x_src, x_src0, qW, qW0, qb0, qng0, kvW, kvW0, kvb0,
      qmixN, q0N, kvmixN, kv0N, N);
  // CSR build (used by fast path; cheap)
  count_kernel<<<(E + 255) / 256, 256, 0, stream>>>(edge, cnt, E);
  scan_kernel<<<1, 1024, 0, stream>>>(cnt, rowstart, N);
  fill_kernel<<<(E + 255) / 256, 256, 0, stream>>>(edge, rowstart, cursor, csr, E);

  for (int e0 = 0; e0 < E; e0 += (int)CE) {
    int cnt_ = E - e0 < (int)CE ? E - e0 : (int)CE;
    radial_mfma<<<(cnt_ + 127) / 128, 256, 0, stream>>>(
        ef, W1T, W2T, W3T, r_b1, r_g1, r_be1, r_b2, r_g2, r_be2, r_b3, w_chunk, e0, E);
    if (fast)
      edgeA_kernel<1><<<cnt_ / 4, 256, 0, stream>>>(qmixN, q0N, kvmixN, kv0N, Rw, edge,
                                                    w_chunk, e0, qng, kng, kng0,
                                                    vb, v0b, logits, mxb, E);
    else
      edgeA_kernel<0><<<cnt_ / 4, 256, 0, stream>>>(qmixN, q0N, kvmixN, kv0N, Rw, edge,
                                                    w_chunk, e0, qng, kng, kng0,
                                                    vb, v0b, logits, mxb, E);
  }
  float* att  = out;
  float* att0 = out + (size_t)N * 160;
  if (fast) {
    nodegather_kernel<<<(N + 3) / 4, 256, 0, stream>>>(Rw, csr, rowstart, vb, v0b,
                                                       logits, att, att0, N);
  } else {
    edge2_kernel<<<(E * 8 + 255) / 256, 256, 0, stream>>>(edge, logits, mxb, den, E);
    for (int e0 = 0; e0 < E; e0 += (int)CE) {
      int cnt_ = E - e0 < (int)CE ? E - e0 : (int)CE;
      radial_mfma<<<(cnt_ + 127) / 128, 256, 0, stream>>>(
          ef, W1T, W2T, W3T, r_b1, r_g1, r_be1, r_b2, r_g2, r_be2, r_b3, w_chunk, e0, E);
      edgeB_rec<<<cnt_ / 4, 256, 0, stream>>>(kvmixN, kv0N, Rw, edge, w_chunk, e0,
                                              logits, mxb, den, att, att0, E);
    }
  }
  node_kernel<<<(N + 3) / 4, 256, 0, stream>>>(pW, pW0, pb0, out, N);
}

// Round 7
// 347.261 us; speedup vs baseline: 2.2815x; 1.4245x over previous
//
#include <hip/hip_runtime.h>
#include <hip/hip_bf16.h>
#include <math.h>

// N=10000, E=160000, C=16, C0=32, L=2, M=5, H=8, R_IN=32, R_HID=128, REQ=384

typedef short bf16x8 __attribute__((ext_vector_type(8)));
typedef float f32x4 __attribute__((ext_vector_type(4)));
typedef unsigned short ushort8v __attribute__((ext_vector_type(8)));

__device__ __forceinline__ float waveSum(float v) {
#pragma unroll
  for (int m = 1; m < 64; m <<= 1) v += __shfl_xor(v, m, 64);
  return v;
}
__device__ __forceinline__ unsigned encf(float f) {
  unsigned u = __float_as_uint(f);
  return (u & 0x80000000u) ? ~u : (u | 0x80000000u);
}
__device__ __forceinline__ float decf(unsigned u) {
  return (u & 0x80000000u) ? __uint_as_float(u & 0x7FFFFFFFu) : __uint_as_float(~u);
}
__device__ __forceinline__ unsigned short f2bu(float f) {
  __hip_bfloat16 h = __float2bfloat16(f);
  unsigned short u;
  __builtin_memcpy(&u, &h, 2);
  return u;
}
__device__ __forceinline__ float bu2f(unsigned u16) {
  unsigned x = u16 << 16;
  float f;
  __builtin_memcpy(&f, &x, 4);
  return f;
}

// ---------------------------------------------------------------------------
// Prep: transpose radial weights to bf16 [n][k] layout
// ---------------------------------------------------------------------------
__global__ __launch_bounds__(256) void prep_kernel(
    const float* __restrict__ W1, const float* __restrict__ W2,
    const float* __restrict__ W3,
    unsigned short* __restrict__ W1T, unsigned short* __restrict__ W2T,
    unsigned short* __restrict__ W3T) {
  int idx = blockIdx.x * 256 + threadIdx.x;
  if (idx < 128 * 32) {
    int n = idx >> 5, k = idx & 31;
    W1T[idx] = f2bu(W1[k * 128 + n]);
  }
  int i2 = idx - 128 * 32;
  if (i2 >= 0 && i2 < 128 * 128) {
    int n = i2 >> 7, k = i2 & 127;
    W2T[i2] = f2bu(W2[k * 128 + n]);
  }
  int i3 = idx - 128 * 32 - 128 * 128;
  if (i3 >= 0 && i3 < 384 * 128) {
    int n = i3 >> 7, k = i3 & 127;
    W3T[i3] = f2bu(W3[k * 384 + n]);
  }
}

// ---------------------------------------------------------------------------
// CSR build: count, scan (1 block), fill
// ---------------------------------------------------------------------------
__global__ __launch_bounds__(256) void count_kernel(const int* __restrict__ edge,
                                                    int* __restrict__ cnt, int E) {
  int e = blockIdx.x * 256 + threadIdx.x;
  if (e < E) atomicAdd(&cnt[edge[E + e]], 1);
}

__global__ __launch_bounds__(1024) void scan_kernel(const int* __restrict__ cnt,
                                                    int* __restrict__ rowstart, int N) {
  __shared__ int sp[1024];
  const int t = threadIdx.x;
  const int chunk = (N + 1023) >> 10;
  const int beg = t * chunk;
  const int end = min(beg + chunk, N);
  int s = 0;
  for (int i = beg; i < end; i++) s += cnt[i];
  sp[t] = s;
  __syncthreads();
  for (int off = 1; off < 1024; off <<= 1) {
    int tmp = (t >= off) ? sp[t - off] : 0;
    __syncthreads();
    sp[t] += tmp;
    __syncthreads();
  }
  int excl = sp[t] - s;
  int run = excl;
  for (int i = beg; i < end; i++) { rowstart[i] = run; run += cnt[i]; }
  if (t == 0) rowstart[N] = sp[1023];
}

__global__ __launch_bounds__(256) void fill_kernel(const int* __restrict__ edge,
                                                   const int* __restrict__ rowstart,
                                                   int* __restrict__ cursor,
                                                   int* __restrict__ csr, int E) {
  int e = blockIdx.x * 256 + threadIdx.x;
  if (e < E) {
    int d = edge[E + e];
    int p = atomicAdd(&cursor[d], 1);
    csr[rowstart[d] + p] = e;
  }
}

// ---------------------------------------------------------------------------
// Node prep: hoist channel-mix GEMMs from edges to nodes.
// ---------------------------------------------------------------------------
__global__ __launch_bounds__(256) void nodeprep_kernel(
    const float* __restrict__ xt, const float* __restrict__ xt0,
    const float* __restrict__ xs, const float* __restrict__ xs0,
    const float* __restrict__ qW, const float* __restrict__ qW0,
    const float* __restrict__ qb0, const float* __restrict__ qng0,
    const float* __restrict__ kvW, const float* __restrict__ kvW0,
    const float* __restrict__ kvb0,
    float* __restrict__ qmixN, float* __restrict__ q0N,
    float* __restrict__ kvmixN, float* __restrict__ kv0N, int N) {
  __shared__ float sXT[4][160];
  __shared__ float sXS[4][160];
  __shared__ float sX0T[4][32];
  __shared__ float sX0S[4][32];
  const int tid = threadIdx.x, wv = tid >> 6, w = tid & 63;
  const int n = blockIdx.x * 4 + wv;
  if (n < N) {
    for (int i = w; i < 160; i += 64) {
      sXT[wv][i] = xt[(size_t)n * 160 + i];
      sXS[wv][i] = xs[(size_t)n * 160 + i];
    }
    if (w < 32) { sX0T[wv][w] = xt0[n * 32 + w]; sX0S[wv][w] = xs0[n * 32 + w]; }
  }
  __syncthreads();
  if (n >= N) return;
  for (int i = w; i < 160; i += 64) {
    int o = i / 10, lm = i % 10, l = lm / 5;
    const float4* wr = (const float4*)(qW + l * 256 + o * 16);
    float a = 0.f;
#pragma unroll
    for (int c4 = 0; c4 < 4; c4++) {
      float4 ww = wr[c4];
      a += ww.x * sXT[wv][(c4 * 4 + 0) * 10 + lm] + ww.y * sXT[wv][(c4 * 4 + 1) * 10 + lm]
         + ww.z * sXT[wv][(c4 * 4 + 2) * 10 + lm] + ww.w * sXT[wv][(c4 * 4 + 3) * 10 + lm];
    }
    qmixN[(size_t)n * 160 + i] = a;
  }
  for (int i = w; i < 320; i += 64) {
    int o = i / 10, lm = i % 10, l = lm / 5;
    const float4* wr = (const float4*)(kvW + l * 512 + o * 16);
    float a = 0.f;
#pragma unroll
    for (int c4 = 0; c4 < 4; c4++) {
      float4 ww = wr[c4];
      a += ww.x * sXS[wv][(c4 * 4 + 0) * 10 + lm] + ww.y * sXS[wv][(c4 * 4 + 1) * 10 + lm]
         + ww.z * sXS[wv][(c4 * 4 + 2) * 10 + lm] + ww.w * sXS[wv][(c4 * 4 + 3) * 10 + lm];
    }
    kvmixN[(size_t)n * 320 + i] = a;
  }
  {
    float a = 0.f;
    if (w < 32) {
      a = qb0[w];
      const float4* wr = (const float4*)(qW0 + w * 32);
#pragma unroll
      for (int c4 = 0; c4 < 8; c4++) {
        float4 ww = wr[c4];
        a += ww.x * sX0T[wv][c4 * 4] + ww.y * sX0T[wv][c4 * 4 + 1]
           + ww.z * sX0T[wv][c4 * 4 + 2] + ww.w * sX0T[wv][c4 * 4 + 3];
      }
    }
    float vv = (w < 32) ? a : 0.f;
    float s1 = waveSum(vv), s2 = waveSum(vv * vv);
    float mu = s1 / 32.f, var = s2 / 32.f - mu * mu;
    if (w < 32) q0N[(size_t)n * 32 + w] = (a - mu) * rsqrtf(var + 1e-5f) * qng0[w];
  }
  {
    float a = kvb0[w];
    const float4* wr = (const float4*)(kvW0 + w * 32);
#pragma unroll
    for (int c4 = 0; c4 < 8; c4++) {
      float4 ww = wr[c4];
      a += ww.x * sX0S[wv][c4 * 4] + ww.y * sX0S[wv][c4 * 4 + 1]
         + ww.z * sX0S[wv][c4 * 4 + 2] + ww.w * sX0S[wv][c4 * 4 + 3];
    }
    kv0N[(size_t)n * 64 + w] = a;
  }
}

// ---------------------------------------------------------------------------
// Kernel 1: MFMA radial MLP.  Output w_chunk in bf16 (halves the round-trip).
// ---------------------------------------------------------------------------
__global__ __launch_bounds__(256) void radial_mfma(
    const float* __restrict__ ef,
    const unsigned short* __restrict__ W1T, const unsigned short* __restrict__ W2T,
    const unsigned short* __restrict__ W3T,
    const float* __restrict__ b1, const float* __restrict__ g1, const float* __restrict__ be1,
    const float* __restrict__ b2, const float* __restrict__ g2, const float* __restrict__ be2,
    const float* __restrict__ b3,
    unsigned short* __restrict__ w_chunk, int e0, int E) {
  __shared__ unsigned short sA[128 * 128];
  __shared__ unsigned short sW[128 * 128];
  const int tid = threadIdx.x;
  const int lane = tid & 63, wid = tid >> 6;
  const int eb = blockIdx.x * 128;
  const int colq = lane & 15, rowq = lane >> 4;

  float b1v[8], g1v[8], be1v[8], b2v[8], g2v[8], be2v[8];
#pragma unroll
  for (int nt = 0; nt < 8; nt++) {
    int c = nt * 16 + colq;
    b1v[nt] = b1[c]; g1v[nt] = g1[c]; be1v[nt] = be1[c];
    b2v[nt] = b2[c]; g2v[nt] = g2[c]; be2v[nt] = be2[c];
  }

  for (int idx = tid; idx < 1024; idx += 256) {
    int e = idx >> 3, k4 = idx & 7;
    int ee = e0 + eb + e; if (ee >= E) ee = E - 1;
    float4 v = *(const float4*)&ef[(size_t)ee * 32 + k4 * 4];
    ushort4 uu = make_ushort4(f2bu(v.x), f2bu(v.y), f2bu(v.z), f2bu(v.w));
    unsigned bo = (unsigned)e * 256 + (((unsigned)k4 * 8) ^ ((e & 7) << 4));
    *(ushort4*)((char*)sA + bo) = uu;
  }
  for (int idx = tid; idx < 512; idx += 256) {
    int n = idx >> 2, j = idx & 3;
    uint4 v = *(const uint4*)&W1T[n * 32 + j * 8];
    unsigned bo = (unsigned)n * 256 + (((unsigned)j * 16) ^ ((n & 7) << 4));
    *(uint4*)((char*)sW + bo) = v;
  }
  __syncthreads();

  f32x4 zz = {0.f, 0.f, 0.f, 0.f};
  f32x4 acc[2][8];
#pragma unroll
  for (int mt = 0; mt < 2; mt++)
#pragma unroll
    for (int nt = 0; nt < 8; nt++) acc[mt][nt] = zz;

  {
    bf16x8 af[2];
#pragma unroll
    for (int mt = 0; mt < 2; mt++) {
      int row = wid * 32 + mt * 16 + colq;
      unsigned bo = (unsigned)row * 256 + (((unsigned)rowq * 16) ^ ((row & 7) << 4));
      af[mt] = *(const bf16x8*)((const char*)sA + bo);
    }
#pragma unroll
    for (int nt = 0; nt < 8; nt++) {
      int n = nt * 16 + colq;
      unsigned bo = (unsigned)n * 256 + (((unsigned)rowq * 16) ^ ((n & 7) << 4));
      bf16x8 bfv = *(const bf16x8*)((const char*)sW + bo);
#pragma unroll
      for (int mt = 0; mt < 2; mt++)
        acc[mt][nt] = __builtin_amdgcn_mfma_f32_16x16x32_bf16(af[mt], bfv, acc[mt][nt], 0, 0, 0);
    }
  }
  __syncthreads();

#pragma unroll
  for (int mt = 0; mt < 2; mt++) {
#pragma unroll
    for (int r = 0; r < 4; r++) {
      float s1 = 0.f, s2 = 0.f;
#pragma unroll
      for (int nt = 0; nt < 8; nt++) {
        float v = acc[mt][nt][r] + b1v[nt];
        s1 += v; s2 += v * v;
      }
#pragma unroll
      for (int off = 1; off < 16; off <<= 1) { s1 += __shfl_xor(s1, off, 64); s2 += __shfl_xor(s2, off, 64); }
      float mu = s1 * (1.f / 128.f);
      float rs = rsqrtf(s2 * (1.f / 128.f) - mu * mu + 1e-5f);
      int row = wid * 32 + mt * 16 + rowq * 4 + r;
      unsigned rbase = (unsigned)row * 256;
      unsigned swz = (row & 7) << 4;
#pragma unroll
      for (int nt = 0; nt < 8; nt++) {
        float v = (acc[mt][nt][r] + b1v[nt] - mu) * rs * g1v[nt] + be1v[nt];
        v = v / (1.f + __expf(-v));
        *(unsigned short*)((char*)sA + rbase + ((((unsigned)(nt * 16 + colq)) * 2) ^ swz)) = f2bu(v);
      }
    }
  }
  for (int idx = tid; idx < 2048; idx += 256) {
    int n = idx >> 4, j = idx & 15;
    uint4 v = *(const uint4*)&W2T[n * 128 + j * 8];
    unsigned bo = (unsigned)n * 256 + (((unsigned)j * 16) ^ ((n & 7) << 4));
    *(uint4*)((char*)sW + bo) = v;
  }
  __syncthreads();

#pragma unroll
  for (int mt = 0; mt < 2; mt++)
#pragma unroll
    for (int nt = 0; nt < 8; nt++) acc[mt][nt] = zz;
#pragma unroll
  for (int ks = 0; ks < 4; ks++) {
    bf16x8 af[2];
#pragma unroll
    for (int mt = 0; mt < 2; mt++) {
      int row = wid * 32 + mt * 16 + colq;
      unsigned bo = (unsigned)row * 256 + (((unsigned)(ks * 64 + rowq * 16)) ^ ((row & 7) << 4));
      af[mt] = *(const bf16x8*)((const char*)sA + bo);
    }
#pragma unroll
    for (int nt = 0; nt < 8; nt++) {
      int n = nt * 16 + colq;
      unsigned bo = (unsigned)n * 256 + (((unsigned)(ks * 64 + rowq * 16)) ^ ((n & 7) << 4));
      bf16x8 bfv = *(const bf16x8*)((const char*)sW + bo);
#pragma unroll
      for (int mt = 0; mt < 2; mt++)
        acc[mt][nt] = __builtin_amdgcn_mfma_f32_16x16x32_bf16(af[mt], bfv, acc[mt][nt], 0, 0, 0);
    }
  }
  __syncthreads();

#pragma unroll
  for (int mt = 0; mt < 2; mt++) {
#pragma unroll
    for (int r = 0; r < 4; r++) {
      float s1 = 0.f, s2 = 0.f;
#pragma unroll
      for (int nt = 0; nt < 8; nt++) {
        float v = acc[mt][nt][r] + b2v[nt];
        s1 += v; s2 += v * v;
      }
#pragma unroll
      for (int off = 1; off < 16; off <<= 1) { s1 += __shfl_xor(s1, off, 64); s2 += __shfl_xor(s2, off, 64); }
      float mu = s1 * (1.f / 128.f);
      float rs = rsqrtf(s2 * (1.f / 128.f) - mu * mu + 1e-5f);
      int row = wid * 32 + mt * 16 + rowq * 4 + r;
      unsigned rbase = (unsigned)row * 256;
      unsigned swz = (row & 7) << 4;
#pragma unroll
      for (int nt = 0; nt < 8; nt++) {
        float v = (acc[mt][nt][r] + b2v[nt] - mu) * rs * g2v[nt] + be2v[nt];
        v = v / (1.f + __expf(-v));
        *(unsigned short*)((char*)sA + rbase + ((((unsigned)(nt * 16 + colq)) * 2) ^ swz)) = f2bu(v);
      }
    }
  }

  for (int cc = 0; cc < 3; cc++) {
    if (cc > 0) __syncthreads();
    for (int idx = tid; idx < 2048; idx += 256) {
      int n = idx >> 4, j = idx & 15;
      uint4 v = *(const uint4*)&W3T[(size_t)(cc * 128 + n) * 128 + j * 8];
      unsigned bo = (unsigned)n * 256 + (((unsigned)j * 16) ^ ((n & 7) << 4));
      *(uint4*)((char*)sW + bo) = v;
    }
    __syncthreads();
    f32x4 a3[2][8];
#pragma unroll
    for (int mt = 0; mt < 2; mt++)
#pragma unroll
      for (int nt = 0; nt < 8; nt++) a3[mt][nt] = zz;
#pragma unroll
    for (int ks = 0; ks < 4; ks++) {
      bf16x8 af[2];
#pragma unroll
      for (int mt = 0; mt < 2; mt++) {
        int row = wid * 32 + mt * 16 + colq;
        unsigned bo = (unsigned)row * 256 + (((unsigned)(ks * 64 + rowq * 16)) ^ ((row & 7) << 4));
        af[mt] = *(const bf16x8*)((const char*)sA + bo);
      }
#pragma unroll
      for (int nt = 0; nt < 8; nt++) {
        int n = nt * 16 + colq;
        unsigned bo = (unsigned)n * 256 + (((unsigned)(ks * 64 + rowq * 16)) ^ ((n & 7) << 4));
        bf16x8 bfv = *(const bf16x8*)((const char*)sW + bo);
#pragma unroll
        for (int mt = 0; mt < 2; mt++)
          a3[mt][nt] = __builtin_amdgcn_mfma_f32_16x16x32_bf16(af[mt], bfv, a3[mt][nt], 0, 0, 0);
      }
    }
#pragma unroll
    for (int nt = 0; nt < 8; nt++) {
      int col = cc * 128 + nt * 16 + colq;
      float b3v = b3[col];
#pragma unroll
      for (int mt = 0; mt < 2; mt++) {
#pragma unroll
        for (int r = 0; r < 4; r++) {
          int row_e = eb + wid * 32 + mt * 16 + rowq * 4 + r;
          w_chunk[(size_t)row_e * 384 + col] = f2bu(a3[mt][nt][r] + b3v);
        }
      }
    }
  }
}

// ---------------------------------------------------------------------------
// Kernel 2: per-edge rotate+conv+norm+logits, REGISTER-ONLY.
// ---------------------------------------------------------------------------
template <int STOREV>
__global__ __launch_bounds__(256) void edgeA_kernel(
    const float* __restrict__ qmixN, const float* __restrict__ q0N,
    const float* __restrict__ kvmixN, const float* __restrict__ kv0N,
    const float* __restrict__ Rw, const int* __restrict__ edge,
    const unsigned short* __restrict__ w_chunk, int e0,
    const float* __restrict__ qng, const float* __restrict__ kng,
    const float* __restrict__ kng0,
    __hip_bfloat16* __restrict__ v_buf, __hip_bfloat16* __restrict__ v0_buf,
    float* __restrict__ logits, unsigned* __restrict__ mx, int E) {
  const int g = threadIdx.x & 63;
  const int e = e0 + blockIdx.x * 4 + (threadIdx.x >> 6);
  const int src = edge[e], dst = edge[E + e];
  const int l = g & 1, cg = g >> 1;

  float R[5][5];
  {
    const float* rb = Rw + (size_t)e * 50 + l * 25;
#pragma unroll
    for (int m = 0; m < 5; m++)
#pragma unroll
      for (int n = 0; n < 5; n++) R[m][n] = rb[m * 5 + n];
  }
  float xr[5];
  {
    const float* xb = kvmixN + (size_t)src * 320 + g * 5;
    float x0 = xb[0], x1 = xb[1], x2 = xb[2], x3 = xb[3], x4 = xb[4];
#pragma unroll
    for (int m = 0; m < 5; m++)
      xr[m] = R[m][0] * x0 + R[m][1] * x1 + R[m][2] * x2 + R[m][3] * x3 + R[m][4] * x4;
  }
  const unsigned short* wa = w_chunk + (size_t)(e - e0) * 384;
  ushort4 wq = *(const ushort4*)(wa + 4 * g);
  float w0_ = bu2f(wq.x), w1_ = bu2f(wq.y), w2_ = bu2f(wq.z), w3_ = bu2f(wq.w);
  float wm = bu2f(wa[320 + g]);
  float y[5];
  y[0] = w3_ * xr[4] + w1_ * xr[0];
  y[1] = w2_ * xr[3] + w0_ * xr[1];
  y[2] = wm * xr[2];
  y[3] = w0_ * xr[3] - w2_ * xr[1];
  y[4] = w1_ * xr[4] - w3_ * xr[0];
  float y0 = bu2f(wa[256 + g]) * kv0N[(size_t)src * 64 + g];

  float p = 0.f;
  if (g < 32) p = y[0] * y[0] + y[1] * y[1] + y[2] * y[2] + y[3] * y[3] + y[4] * y[4];
  float rmsk = rsqrtf(waveSum(p) * (1.f / 160.f) + 1e-5f);
  float kngc = (g < 32) ? kng[cg] : 0.f;
  float yk[5];
#pragma unroll
  for (int m = 0; m < 5; m++) yk[m] = y[m] * rmsk * kngc;
  float k0v = (g < 32) ? y0 : 0.f;
  float s1 = waveSum(k0v), s2 = waveSum(k0v * k0v);
  float mu = s1 * (1.f / 32.f), var = s2 * (1.f / 32.f) - mu * mu;
  float k0n = (k0v - mu) * rsqrtf(var + 1e-5f) * ((g < 32) ? kng0[g] : 0.f);

  float qn[5];
  float q0 = 0.f;
  {
    float qx0 = 0.f, qx1 = 0.f, qx2 = 0.f, qx3 = 0.f, qx4 = 0.f;
    if (g < 32) {
      const float* qb = qmixN + (size_t)dst * 160 + g * 5;
      qx0 = qb[0]; qx1 = qb[1]; qx2 = qb[2]; qx3 = qb[3]; qx4 = qb[4];
      q0 = q0N[(size_t)dst * 32 + g];
    }
    float qr[5];
#pragma unroll
    for (int m = 0; m < 5; m++)
      qr[m] = R[m][0] * qx0 + R[m][1] * qx1 + R[m][2] * qx2 + R[m][3] * qx3 + R[m][4] * qx4;
    float pq = qr[0] * qr[0] + qr[1] * qr[1] + qr[2] * qr[2] + qr[3] * qr[3] + qr[4] * qr[4];
    float rmsq = rsqrtf(waveSum(pq) * (1.f / 160.f) + 1e-5f);
    float qngc = (g < 32) ? qng[cg] : 0.f;
#pragma unroll
    for (int m = 0; m < 5; m++) qn[m] = qr[m] * rmsq * qngc;
  }

  float part = qn[0] * yk[0] + qn[1] * yk[1] + qn[2] * yk[2] + qn[3] * yk[3] + qn[4] * yk[4]
             + q0 * k0n;
  part += __shfl_xor(part, 1, 64);
  part += __shfl_xor(part, 2, 64);
  if (g < 32 && (g & 3) == 0) {
    int h = g >> 2;
    float lg = part * 0.70710678118654752f;
    logits[(size_t)e * 8 + h] = lg;
    if (!STOREV) atomicMax(&mx[dst * 8 + h], encf(lg));
  }
  if (STOREV && g >= 32) {
    int j = g - 32;
    ushort8v pk;
    pk[0] = f2bu(y[0]); pk[1] = f2bu(y[1]); pk[2] = f2bu(y[2]);
    pk[3] = f2bu(y[3]); pk[4] = f2bu(y[4]); pk[5] = 0; pk[6] = 0; pk[7] = 0;
    *(ushort8v*)((char*)v_buf + ((size_t)e * 256 + j * 8) * 2) = pk;
    v0_buf[(size_t)e * 32 + j] = __float2bfloat16(y0);
  }
}

// ---------------------------------------------------------------------------
// Kernel 3 (fallback only): denominator
// ---------------------------------------------------------------------------
__global__ __launch_bounds__(256) void edge2_kernel(
    const int* __restrict__ edge, const float* __restrict__ logits,
    const unsigned* __restrict__ mx, float* __restrict__ den, int E) {
  int idx = blockIdx.x * 256 + threadIdx.x;
  if (idx >= E * 8) return;
  int e = idx >> 3, h = idx & 7;
  int dst = edge[E + e];
  float m = decf(mx[dst * 8 + h]);
  atomicAdd(&den[dst * 8 + h], __expf(logits[idx] - m));
}

// ---------------------------------------------------------------------------
// Kernel 4 (fast): per-NODE gather, parity-split (2 edges in flight/wave),
// fused 2-pass softmax, register accumulate, plain stores.  NO ATOMICS.
// Lane g: edge parity ep=g>>5, group gg=g&31 (c=gg>>1,l=gg&1,h=gg>>2).
// ---------------------------------------------------------------------------
__global__ __launch_bounds__(256) void nodegather_kernel(
    const float* __restrict__ Rw, const int* __restrict__ csr,
    const int* __restrict__ rowstart,
    const __hip_bfloat16* __restrict__ v_buf, const __hip_bfloat16* __restrict__ v0_buf,
    const float* __restrict__ logits,
    float* __restrict__ att, float* __restrict__ att0, int N) {
  const int g = threadIdx.x & 63;
  const int n = blockIdx.x * 4 + (threadIdx.x >> 6);
  if (n >= N) return;
  const int row = rowstart[n];
  const int deg = rowstart[n + 1] - row;
  const int ep = g >> 5, gg = g & 31;
  const int l = gg & 1, h = gg >> 2;

  if (deg == 0) {
    if (g < 32) {
#pragma unroll
      for (int m = 0; m < 5; m++) att[(size_t)n * 160 + gg * 5 + m] = 0.f;
      att0[(size_t)n * 32 + gg] = 0.f;
    }
    return;
  }

  // pass 1: per-head max (parity-split, combined by shfl)
  float mxh = -3.402823466e38f;
  for (int k = ep; k < deg; k += 2)
    mxh = fmaxf(mxh, logits[(size_t)csr[row + k] * 8 + h]);
  mxh = fmaxf(mxh, __shfl_xor(mxh, 32, 64));

  // pass 2: fused denominator + weighted accumulate
  float acc[5] = {0.f, 0.f, 0.f, 0.f, 0.f};
  float acc0 = 0.f, den = 0.f;
  for (int k = ep; k < deg; k += 2) {
    int e = csr[row + k];
    float ex = __expf(logits[(size_t)e * 8 + h] - mxh);
    den += ex;
    uint4 vv = *(const uint4*)((const char*)v_buf + ((size_t)e * 256 + gg * 8) * 2);
    float v0_ = bu2f(vv.x & 0xffffu), v1_ = bu2f(vv.x >> 16);
    float v2_ = bu2f(vv.y & 0xffffu), v3_ = bu2f(vv.y >> 16);
    float v4_ = bu2f(vv.z & 0xffffu);
    const float* rb = Rw + (size_t)e * 50 + l * 25;
#pragma unroll
    for (int m = 0; m < 5; m++) {
      float o = rb[m] * v0_ + rb[5 + m] * v1_ + rb[10 + m] * v2_ +
                rb[15 + m] * v3_ + rb[20 + m] * v4_;
      acc[m] += ex * o;
    }
    acc0 += ex * __bfloat162float(v0_buf[(size_t)e * 32 + gg]);
  }
  // combine parities
  den += __shfl_xor(den, 32, 64);
#pragma unroll
  for (int m = 0; m < 5; m++) acc[m] += __shfl_xor(acc[m], 32, 64);
  acc0 += __shfl_xor(acc0, 32, 64);
  float inv = 1.f / den;
  if (g < 32) {
#pragma unroll
    for (int m = 0; m < 5; m++) att[(size_t)n * 160 + gg * 5 + m] = acc[m] * inv;
    att0[(size_t)n * 32 + gg] = acc0 * inv;
  }
}

// ---------------------------------------------------------------------------
// Kernel 4b (fallback): recompute v branch, atomic scatter
// ---------------------------------------------------------------------------
__global__ __launch_bounds__(256) void edgeB_rec(
    const float* __restrict__ kvmixN, const float* __restrict__ kv0N,
    const float* __restrict__ Rw, const int* __restrict__ edge,
    const unsigned short* __restrict__ w_chunk, int e0,
    const float* __restrict__ logits, const unsigned* __restrict__ mx,
    const float* __restrict__ den,
    float* __restrict__ att, float* __restrict__ att0, int E) {
  const int g = threadIdx.x & 63;
  const int e = e0 + blockIdx.x * 4 + (threadIdx.x >> 6);
  const int src = edge[e], dst = edge[E + e];
  const int l = g & 1;
  const int h = (g < 32) ? (g >> 2) : ((g - 32) >> 2);
  float m_ = decf(mx[dst * 8 + h]);
  float alpha = __expf(logits[(size_t)e * 8 + h] - m_) / den[dst * 8 + h];
  const unsigned short* wa = w_chunk + (size_t)(e - e0) * 384;
  if (g < 32) {
    const float* rb = Rw + (size_t)e * 50 + l * 25;
    float R[5][5];
#pragma unroll
    for (int a = 0; a < 5; a++)
#pragma unroll
      for (int b = 0; b < 5; b++) R[a][b] = rb[a * 5 + b];
    float xr[5];
    {
      const float* xb = kvmixN + (size_t)src * 320 + 160 + g * 5;
      float x0 = xb[0], x1 = xb[1], x2 = xb[2], x3 = xb[3], x4 = xb[4];
#pragma unroll
      for (int m = 0; m < 5; m++)
        xr[m] = R[m][0] * x0 + R[m][1] * x1 + R[m][2] * x2 + R[m][3] * x3 + R[m][4] * x4;
    }
    ushort4 wq = *(const ushort4*)(wa + (32 + g) * 4);
    float w0_ = bu2f(wq.x), w1_ = bu2f(wq.y), w2_ = bu2f(wq.z), w3_ = bu2f(wq.w);
    float wm = bu2f(wa[352 + g]);
    float y[5];
    y[0] = w3_ * xr[4] + w1_ * xr[0];
    y[1] = w2_ * xr[3] + w0_ * xr[1];
    y[2] = wm * xr[2];
    y[3] = w0_ * xr[3] - w2_ * xr[1];
    y[4] = w1_ * xr[4] - w3_ * xr[0];
#pragma unroll
    for (int m = 0; m < 5; m++) {
      float o = R[0][m] * y[0] + R[1][m] * y[1] + R[2][m] * y[2] + R[3][m] * y[3] + R[4][m] * y[4];
      atomicAdd(&att[(size_t)dst * 160 + g * 5 + m], alpha * o);
    }
  } else {
    int j = g - 32;
    float v0 = bu2f(wa[288 + j]) * kv0N[(size_t)src * 64 + 32 + j];
    atomicAdd(&att0[(size_t)dst * 32 + j], alpha * v0);
  }
}

// ---------------------------------------------------------------------------
// Kernel 5: per-node output projection, in place over d_out
// ---------------------------------------------------------------------------
__global__ __launch_bounds__(256) void node_kernel(
    const float* __restrict__ pW, const float* __restrict__ pW0,
    const float* __restrict__ pb0, float* __restrict__ out, int N) {
  __shared__ float sA[4][160];
  __shared__ float sA0[4][32];
  const int tid = threadIdx.x;
  const int wv = tid >> 6, w = tid & 63;
  const int n = blockIdx.x * 4 + wv;
  if (n < N) {
    for (int i = w; i < 160; i += 64) sA[wv][i] = out[(size_t)n * 160 + i];
    if (w < 32) sA0[wv][w] = out[(size_t)N * 160 + (size_t)n * 32 + w];
  }
  __syncthreads();
  if (n >= N) return;
  for (int i = w; i < 160; i += 64) {
    int o = i / 10, lm = i % 10, l = lm / 5, m = lm % 5;
    float a = 0.f;
    const float* wr = pW + l * 256 + o * 16;
#pragma unroll
    for (int c = 0; c < 16; c++) a += wr[c] * sA[wv][c * 10 + l * 5 + m];
    out[(size_t)n * 160 + i] = a;
  }
  if (w < 32) {
    float a = pb0[w];
    const float* wr = pW0 + w * 32;
#pragma unroll
    for (int c = 0; c < 32; c++) a += wr[c] * sA0[wv][c];
    out[(size_t)N * 160 + (size_t)n * 32 + w] = a;
  }
}

// ---------------------------------------------------------------------------
extern "C" void kernel_launch(void* const* d_in, const int* in_sizes, int n_in,
                              void* d_out, int out_size, void* d_ws, size_t ws_size,
                              hipStream_t stream) {
  const float* x_src  = (const float*)d_in[0];
  const float* x_tar  = (const float*)d_in[1];
  const float* x_src0 = (const float*)d_in[2];
  const float* x_tar0 = (const float*)d_in[3];
  const float* Rw     = (const float*)d_in[4];
  const float* ef     = (const float*)d_in[5];
  const int*   edge   = (const int*)d_in[6];
  const float* r_W1 = (const float*)d_in[10];
  const float* r_b1 = (const float*)d_in[11];
  const float* r_g1 = (const float*)d_in[12];
  const float* r_be1 = (const float*)d_in[13];
  const float* r_W2 = (const float*)d_in[14];
  const float* r_b2 = (const float*)d_in[15];
  const float* r_g2 = (const float*)d_in[16];
  const float* r_be2 = (const float*)d_in[17];
  const float* r_W3 = (const float*)d_in[18];
  const float* r_b3 = (const float*)d_in[19];
  const float* qW  = (const float*)d_in[20];
  const float* qW0 = (const float*)d_in[21];
  const float* qb0 = (const float*)d_in[22];
  const float* kvW  = (const float*)d_in[23];
  const float* kvW0 = (const float*)d_in[24];
  const float* kvb0 = (const float*)d_in[25];
  const float* qng  = (const float*)d_in[26];
  const float* qng0 = (const float*)d_in[27];
  const float* kng  = (const float*)d_in[28];
  const float* kng0 = (const float*)d_in[29];
  const float* pW  = (const float*)d_in[30];
  const float* pW0 = (const float*)d_in[31];
  const float* pb0 = (const float*)d_in[32];

  const int N = in_sizes[0] / 160;   // 10000
  const int E = in_sizes[4] / 50;    // 160000
  float* out = (float*)d_out;

  char* ws = (char*)d_ws;
  size_t off = 0;
  auto alloc = [&](size_t bytes) {
    void* p = ws + off;
    off += (bytes + 255) & ~(size_t)255;  // keep every buffer 256B-aligned
    return p;
  };
  unsigned short* W1T = (unsigned short*)alloc(128 * 32 * 2);
  unsigned short* W2T = (unsigned short*)alloc(128 * 128 * 2);
  unsigned short* W3T = (unsigned short*)alloc(384 * 128 * 2);
  float* logits = (float*)alloc((size_t)E * 8 * 4);
  int* rowstart = (int*)alloc((size_t)(N + 1) * 4);
  int* csr      = (int*)alloc((size_t)E * 4);
  size_t zoff = off;
  int* cnt    = (int*)alloc((size_t)N * 4);
  int* cursor = (int*)alloc((size_t)N * 4);
  unsigned* mxb = (unsigned*)alloc((size_t)N * 8 * 4);
  float* den = (float*)alloc((size_t)N * 8 * 4);
  size_t zend = off;
  float* qmixN  = (float*)alloc((size_t)N * 160 * 4);
  float* q0N    = (float*)alloc((size_t)N * 32 * 4);
  float* kvmixN = (float*)alloc((size_t)N * 320 * 4);
  float* kv0N   = (float*)alloc((size_t)N * 64 * 4);

  if (ws_size <= off + 128 * 384 * 2) return;
  size_t avail = ws_size - off;
  const size_t vsz = (size_t)E * 256 * 2 + (size_t)E * 32 * 2 + 512;
  bool fast = false;
  size_t CE;
  __hip_bfloat16 *vb = nullptr, *v0b = nullptr;
  if (avail >= vsz + (size_t)1024 * 384 * 2) {
    fast = true;
    vb  = (__hip_bfloat16*)alloc((size_t)E * 256 * 2);
    v0b = (__hip_bfloat16*)alloc((size_t)E * 32 * 2);
    CE = (ws_size - off) / (384 * 2);
  } else {
    CE = avail / (384 * 2);
  }
  if (CE > (size_t)E) CE = E;
  CE &= ~(size_t)127;
  if (CE == 0) return;
  unsigned short* w_chunk = (unsigned short*)(ws + off);

  hipMemsetAsync(ws + zoff, 0, zend - zoff, stream);
  hipMemsetAsync(d_out, 0, (size_t)out_size * 4, stream);

  prep_kernel<<<(69632 + 255) / 256, 256, 0, stream>>>(r_W1, r_W2, r_W3, W1T, W2T, W3T);
  nodeprep_kernel<<<(N + 3) / 4, 256, 0, stream>>>(
      x_tar, x_tar0, x_src, x_src0, qW, qW0, qb0, qng0, kvW, kvW0, kvb0,
      qmixN, q0N, kvmixN, kv0N, N);
  count_kernel<<<(E + 255) / 256, 256, 0, stream>>>(edge, cnt, E);
  scan_kernel<<<1, 1024, 0, stream>>>(cnt, rowstart, N);
  fill_kernel<<<(E + 255) / 256, 256, 0, stream>>>(edge, rowstart, cursor, csr, E);

  for (int e0 = 0; e0 < E; e0 += (int)CE) {
    int cnt_ = E - e0 < (int)CE ? E - e0 : (int)CE;
    radial_mfma<<<(cnt_ + 127) / 128, 256, 0, stream>>>(
        ef, W1T, W2T, W3T, r_b1, r_g1, r_be1, r_b2, r_g2, r_be2, r_b3, w_chunk, e0, E);
    if (fast)
      edgeA_kernel<1><<<cnt_ / 4, 256, 0, stream>>>(qmixN, q0N, kvmixN, kv0N, Rw, edge,
                                                    w_chunk, e0, qng, kng, kng0,
                                                    vb, v0b, logits, mxb, E);
    else
      edgeA_kernel<0><<<cnt_ / 4, 256, 0, stream>>>(qmixN, q0N, kvmixN, kv0N, Rw, edge,
                                                    w_chunk, e0, qng, kng, kng0,
                                                    vb, v0b, logits, mxb, E);
  }
  float* att  = out;
  float* att0 = out + (size_t)N * 160;
  if (fast) {
    nodegather_kernel<<<(N + 3) / 4, 256, 0, stream>>>(Rw, csr, rowstart, vb, v0b,
                                                       logits, att, att0, N);
  } else {
    edge2_kernel<<<(E * 8 + 255) / 256, 256, 0, stream>>>(edge, logits, mxb, den, E);
    for (int e0 = 0; e0 < E; e0 += (int)CE) {
      int cnt_ = E - e0 < (int)CE ? E - e0 : (int)CE;
      radial_mfma<<<(cnt_ + 127) / 128, 256, 0, stream>>>(
          ef, W1T, W2T, W3T, r_b1, r_g1, r_be1, r_b2, r_g2, r_be2, r_b3, w_chunk, e0, E);
      edgeB_rec<<<cnt_ / 4, 256, 0, stream>>>(kvmixN, kv0N, Rw, edge, w_chunk, e0,
                                              logits, mxb, den, att, att0, E);
    }
  }
  node_kernel<<<(N + 3) / 4, 256, 0, stream>>>(pW, pW0, pb0, out, N);
}